// Round 14
// baseline (827.029 us; speedup 1.0000x reference)
//
#include <hip/hip_runtime.h>

typedef short bf16x8 __attribute__((ext_vector_type(8)));
typedef float f32x4 __attribute__((ext_vector_type(4)));

#define DN 128
#define DE 64
#define DEMB 128
#define DHID 256
#define SCALE 0.08838834764831845f  // 1/sqrt(128)

__device__ __forceinline__ ushort f2bf(float f) {
  unsigned u = __float_as_uint(f);
  return (ushort)((u + 0x7FFFu + ((u >> 16) & 1u)) >> 16);  // RNE
}
__device__ __forceinline__ float bf2f(ushort u) {
  return __uint_as_float((unsigned)u << 16);
}

// ---------- fused weight prep: prep2 (576 blk) | prep1 (128) | prep3 (32) | prep_b (3) ----------
__global__ void k_prep_all(const float* __restrict__ W1, const float* __restrict__ Wq,
                           const float* __restrict__ Wk, const float* __restrict__ Wv,
                           const float* __restrict__ Wr, const float* __restrict__ We,
                           const float* __restrict__ bq, const float* __restrict__ bk,
                           const float* __restrict__ bv, const float* __restrict__ br,
                           const float* __restrict__ be,
                           ushort* __restrict__ Wp1, ushort* __restrict__ Wp2,
                           ushort* __restrict__ Wp3, float* __restrict__ bcat) {
  int bid = blockIdx.x;
  if (bid < 576) {
    int idx = bid * 256 + threadIdx.x;
    int j = idx & 7, lane = (idx >> 3) & 63, s = (idx >> 9) & 7, t = idx >> 12;
    int k = s * 32 + (lane >> 4) * 8 + j;
    int c = t * 16 + (lane & 15);
    float v;
    if (c < 128)       v = Wq[k * DEMB + c] * SCALE;
    else if (c < 256)  v = Wk[k * DEMB + (c - 128)];
    else if (c < 384)  v = Wv[k * DEMB + (c - 256)];
    else if (c < 512)  v = Wr[k * DEMB + (c - 384)];
    else {
      int cc = c - 512;
      float a = 0.f;
      for (int u = 0; u < DEMB; ++u) a += Wq[k * DEMB + u] * We[cc * DEMB + u];
      v = a * SCALE;
    }
    Wp2[idx] = f2bf(v);
  } else if (bid < 704) {
    int idx = (bid - 576) * 256 + threadIdx.x;
    int j = idx & 7, lane = (idx >> 3) & 63, s = (idx >> 9) & 3, t = idx >> 11;
    int k = s * 32 + (lane >> 4) * 8 + j;
    int c = t * 16 + (lane & 15);
    Wp1[idx] = f2bf(W1[k * DHID + c]);
  } else if (bid < 736) {
    int idx = (bid - 704) * 256 + threadIdx.x;
    int j = idx & 7, lane = (idx >> 3) & 63, s = (idx >> 9) & 1, t = idx >> 10;
    int k = s * 32 + (lane >> 4) * 8 + j;
    int c = t * 16 + (lane & 15);
    Wp3[idx] = f2bf(We[k * DEMB + c]);
  } else {
    int j = (bid - 736) * 256 + threadIdx.x;
    if (j >= 576) return;
    float v;
    if (j < 128)       v = bq[j] * SCALE;
    else if (j < 256)  v = bk[j - 128] + be[j - 128];
    else if (j < 384)  v = bv[j - 256] + be[j - 256];
    else if (j < 512)  v = br[j - 384];
    else {
      int cc = j - 512;
      float a = 0.f;
      for (int u = 0; u < DEMB; ++u) a += bq[u] * We[cc * DEMB + u];
      v = a * SCALE;
    }
    bcat[j] = v;
  }
}

// ---------- CSR build ----------
__global__ void k_deg(const int* __restrict__ ei, int* __restrict__ degi, int nE) {
  int e = blockIdx.x * 256 + threadIdx.x;
  if (e < nE) atomicAdd(&degi[ei[nE + e]], 1);
}

__global__ __launch_bounds__(1024) void k_scan(const int* __restrict__ degi,
                                               int* __restrict__ row_ptr,
                                               float* __restrict__ dinv, int n) {
  __shared__ int wsum[16];
  __shared__ int carry_s;
  int lane = threadIdx.x & 63, wid = threadIdx.x >> 6;
  if (threadIdx.x == 0) carry_s = 0;
  __syncthreads();
  for (int base = 0; base < n; base += 1024) {
    int i = base + threadIdx.x;
    int v = (i < n) ? degi[i] : 0;
    if (i < n) dinv[i] = rsqrtf(1.0f + (float)v);
    int sc = v;
    #pragma unroll
    for (int off = 1; off < 64; off <<= 1) {
      int t = __shfl_up(sc, off);
      if (lane >= off) sc += t;
    }
    if (lane == 63) wsum[wid] = sc;
    int carry0 = carry_s;
    __syncthreads();
    if (wid == 0) {
      int w = (lane < 16) ? wsum[lane] : 0;
      int swc = w;
      #pragma unroll
      for (int off = 1; off < 16; off <<= 1) {
        int t = __shfl_up(swc, off);
        if (lane >= off) swc += t;
      }
      if (lane < 16) wsum[lane] = swc - w;
      if (lane == 15) carry_s = carry0 + swc;
    }
    __syncthreads();
    if (i < n) row_ptr[i] = carry0 + wsum[wid] + sc - v;
    __syncthreads();
  }
  if (threadIdx.x == 0) row_ptr[n] = carry_s;
}

__global__ void k_scatter(const int* __restrict__ ei, const int* __restrict__ row_ptr,
                          int* __restrict__ cursor, int2* __restrict__ csr_se, int nE) {
  int e = blockIdx.x * 256 + threadIdx.x;
  if (e >= nE) return;
  int dst = ei[nE + e];
  int pos = row_ptr[dst] + atomicAdd(&cursor[dst], 1);
  csr_se[pos] = make_int2(ei[e], e);
}

// ---------- xcast (+ gbounds fused): xsb[n][128] = bf16(dinv[n]*x[n]) ----------
__global__ __launch_bounds__(256) void k_xcast(const float* __restrict__ x,
                                               const float* __restrict__ dinv,
                                               const int* __restrict__ batch,
                                               int* __restrict__ gstart,
                                               ushort* __restrict__ xsb, int nN, int B) {
  int idx = blockIdx.x * 256 + threadIdx.x;
  if (idx < nN) {
    int b = batch[idx];
    if (idx == 0) {
      for (int g = 0; g <= b; ++g) gstart[g] = 0;
    } else {
      int pb = batch[idx - 1];
      for (int g = pb + 1; g <= b; ++g) gstart[g] = idx;
    }
    if (idx == nN - 1) {
      for (int g = b + 1; g <= B; ++g) gstart[g] = nN;
    }
  }
  if (idx < nN * 32) {
    int n = idx >> 5, q = idx & 31;
    float dn = dinv[n];
    float4 v = *(const float4*)&x[(size_t)n * DN + q * 4];
    ushort4 o;
    o.x = f2bf(v.x * dn); o.y = f2bf(v.y * dn);
    o.z = f2bf(v.z * dn); o.w = f2bf(v.w * dn);
    *(ushort4*)&xsb[(size_t)n * DN + q * 4] = o;
  }
}

// ---------- GCN aggregate, 3-buffer rotation prefetch: wave/node, 4 groups ----------
__global__ __launch_bounds__(256, 4) void k_gcnX(const ushort* __restrict__ xsb,
                                                 const int2* __restrict__ csr_se,
                                                 const int* __restrict__ row_ptr,
                                                 const float* __restrict__ dinv,
                                                 ushort* __restrict__ aggxb, int nN) {
  int lane = threadIdx.x & 63;
  int n = blockIdx.x * 4 + (threadIdx.x >> 6);
  if (n >= nN) return;
  int grp = lane >> 4, l15 = lane & 15;
  int beg = row_ptr[n], end = row_ptr[n + 1];
  float acc[8] = {};

#define GLOAD(X0, X1, base)                                                \
  {                                                                        \
    int e0 = (base) + grp,     c0 = e0 < end ? e0 : end - 1;               \
    int e1 = (base) + 4 + grp, c1 = e1 < end ? e1 : end - 1;               \
    int s0 = csr_se[c0].x, s1 = csr_se[c1].x;                              \
    X0 = *(const uint4*)&xsb[(size_t)s0 * DN + l15 * 8];                   \
    X1 = *(const uint4*)&xsb[(size_t)s1 * DN + l15 * 8];                   \
  }
#define GCOMP(X0, X1, base)                                                \
  {                                                                        \
    float m0 = ((base) + grp < end) ? 1.f : 0.f;                           \
    float m1 = ((base) + 4 + grp < end) ? 1.f : 0.f;                       \
    unsigned q0[4] = {X0.x, X0.y, X0.z, X0.w};                             \
    unsigned q1[4] = {X1.x, X1.y, X1.z, X1.w};                             \
    _Pragma("unroll") for (int d = 0; d < 4; ++d) {                        \
      acc[2*d]   = fmaf(m0, __uint_as_float(q0[d] << 16), acc[2*d]);       \
      acc[2*d+1] = fmaf(m0, __uint_as_float(q0[d] & 0xFFFF0000u), acc[2*d+1]); \
      acc[2*d]   = fmaf(m1, __uint_as_float(q1[d] << 16), acc[2*d]);       \
      acc[2*d+1] = fmaf(m1, __uint_as_float(q1[d] & 0xFFFF0000u), acc[2*d+1]); \
    }                                                                      \
  }

  if (beg < end) {
    uint4 xA0, xA1, xB0, xB1, xC0, xC1;
    int iA = beg, iB = beg + 8, iC = beg + 16;
    GLOAD(xA0, xA1, iA);
    if (iB < end) GLOAD(xB0, xB1, iB);
    while (true) {
      if (iC < end) GLOAD(xC0, xC1, iC);
      GCOMP(xA0, xA1, iA);
      iA = iC + 8;
      if (iB >= end) break;
      if (iA < end) GLOAD(xA0, xA1, iA);
      GCOMP(xB0, xB1, iB);
      iB = iA + 8;
      if (iC >= end) break;
      if (iB < end) GLOAD(xB0, xB1, iB);
      GCOMP(xC0, xC1, iC);
      iC = iB + 8;
      if (iA >= end) break;
    }
  }
#undef GLOAD
#undef GCOMP

  #pragma unroll
  for (int d = 0; d < 8; ++d) {
    acc[d] += __shfl_xor(acc[d], 16);
    acc[d] += __shfl_xor(acc[d], 32);
  }
  if (grp == 0) {
    uint4 sa = *(const uint4*)&xsb[(size_t)n * DN + l15 * 8];
    unsigned sq[4] = {sa.x, sa.y, sa.z, sa.w};
    float dn = dinv[n];
    ushort o[8];
    #pragma unroll
    for (int d = 0; d < 4; ++d) {
      float lo = __uint_as_float(sq[d] << 16);
      float hi = __uint_as_float(sq[d] & 0xFFFF0000u);
      o[2*d]   = f2bf(dn * (acc[2*d]   + lo));
      o[2*d+1] = f2bf(dn * (acc[2*d+1] + hi));
    }
    uint4 ov = {(unsigned)o[0] | ((unsigned)o[1] << 16),
                (unsigned)o[2] | ((unsigned)o[3] << 16),
                (unsigned)o[4] | ((unsigned)o[5] << 16),
                (unsigned)o[6] | ((unsigned)o[7] << 16)};
    *(uint4*)&aggxb[(size_t)n * DN + l15 * 8] = ov;
  }
}

// ---------- fused GEMM1b+GEMM2 via LDS hb tile ----------
// phase A: h = relu(aggxb @ W1 + b1) -> LDS [16][264] bf16 (pad: 2-way conflicts only)
// phase B: [qwb|kvb|hrb] = h @ Wp2 + bcat, A-frags read from LDS
__global__ __launch_bounds__(256) void k_gemm12(const ushort* __restrict__ aggxb,
                                                const ushort* __restrict__ Wp1,
                                                const float* __restrict__ b1,
                                                const ushort* __restrict__ Wp2,
                                                const float* __restrict__ bcat,
                                                ushort* __restrict__ qwb,
                                                ushort* __restrict__ kvb,
                                                ushort* __restrict__ hrb, int nN) {
  __shared__ ushort hlds[16][264];
  int lane = threadIdx.x & 63, wave = threadIdx.x >> 6;
  int l15 = lane & 15, lh = lane >> 4;
  int m0 = blockIdx.x * 16;
  int rowa = m0 + l15; if (rowa >= nN) rowa = nN - 1;
  // ---- phase A ----
  {
    f32x4 acc[4] = {};
    #pragma unroll
    for (int s = 0; s < 4; ++s) {
      bf16x8 af = *(const bf16x8*)&aggxb[(size_t)rowa * DN + s * 32 + lh * 8];
      #pragma unroll
      for (int tt = 0; tt < 4; ++tt) {
        int t = wave * 4 + tt;
        bf16x8 bf = *(const bf16x8*)&Wp1[((t * 4 + s) * 64 + lane) * 8];
        acc[tt] = __builtin_amdgcn_mfma_f32_16x16x32_bf16(af, bf, acc[tt], 0, 0, 0);
      }
    }
    #pragma unroll
    for (int tt = 0; tt < 4; ++tt) {
      int c = (wave * 4 + tt) * 16 + l15;
      float bc = b1[c];
      #pragma unroll
      for (int r = 0; r < 4; ++r)
        hlds[lh * 4 + r][c] = f2bf(fmaxf(acc[tt][r] + bc, 0.f));
    }
  }
  __syncthreads();
  // ---- phase B ----
  {
    f32x4 acc[9] = {};
    for (int s = 0; s < 8; ++s) {
      bf16x8 af = *(const bf16x8*)&hlds[l15][s * 32 + lh * 8];
      #pragma unroll
      for (int tt = 0; tt < 9; ++tt) {
        int t = wave * 9 + tt;
        bf16x8 bf = *(const bf16x8*)&Wp2[((t * 8 + s) * 64 + lane) * 8];
        acc[tt] = __builtin_amdgcn_mfma_f32_16x16x32_bf16(af, bf, acc[tt], 0, 0, 0);
      }
    }
    #pragma unroll
    for (int tt = 0; tt < 9; ++tt) {
      int c = (wave * 9 + tt) * 16 + l15;
      float bc = bcat[c];
      #pragma unroll
      for (int r = 0; r < 4; ++r) {
        int row = m0 + lh * 4 + r;
        if (row >= nN) continue;
        ushort val = f2bf(acc[tt][r] + bc);
        if (c < 128)      qwb[(size_t)row * 192 + c] = val;
        else if (c < 256) { int d = c - 128; kvb[(size_t)row * 256 + (d >> 3) * 16 + (d & 7)] = val; }
        else if (c < 384) { int d = c - 256; kvb[(size_t)row * 256 + (d >> 3) * 16 + 8 + (d & 7)] = val; }
        else if (c < 512) hrb[(size_t)row * 128 + (c - 384)] = val;
        else              qwb[(size_t)row * 192 + 128 + (c - 512)] = val;
      }
    }
  }
}

// ---------- fused attention edge pass: 3-buffer rotation, 4 groups, 2 slots/chunk ----------
__global__ __launch_bounds__(256, 4) void k_edge(const ushort* __restrict__ qwb,
                                                 const ushort* __restrict__ kvb,
                                                 const float* __restrict__ ea32,
                                                 const int2* __restrict__ csr_se,
                                                 const int* __restrict__ row_ptr,
                                                 float* __restrict__ sden,
                                                 float* __restrict__ vaccf,
                                                 ushort* __restrict__ ewb, int nN) {
  int lane = threadIdx.x & 63;
  int n = blockIdx.x * 4 + (threadIdx.x >> 6);
  if (n >= nN) return;
  int grp = lane >> 4, l15 = lane & 15;
  const ushort* qp = &qwb[(size_t)n * 192];
  bf16x8 qv = *(const bf16x8*)&qp[l15 * 8];
  ushort4 wv = *(const ushort4*)&qp[128 + l15 * 4];
  float q[8];
  #pragma unroll
  for (int d = 0; d < 8; ++d) q[d] = bf2f((ushort)qv[d]);
  float w0 = bf2f(wv.x), w1 = bf2f(wv.y), w2 = bf2f(wv.z), w3 = bf2f(wv.w);
  float s_acc = 0.f;
  float av[8] = {};
  float ae[4] = {};
  int beg = row_ptr[n], end = row_ptr[n + 1];

#define ELOAD(K0, K1, V0, V1, E0, E1, base)                                \
  {                                                                        \
    int e0 = (base) + grp,     c0 = e0 < end ? e0 : end - 1;               \
    int e1 = (base) + 4 + grp, c1 = e1 < end ? e1 : end - 1;               \
    int2 se0 = csr_se[c0], se1 = csr_se[c1];                               \
    const ushort* r0 = &kvb[(size_t)se0.x * 256 + l15 * 16];               \
    const ushort* r1 = &kvb[(size_t)se1.x * 256 + l15 * 16];               \
    K0 = *(const bf16x8*)r0;  V0 = *(const bf16x8*)(r0 + 8);               \
    K1 = *(const bf16x8*)r1;  V1 = *(const bf16x8*)(r1 + 8);               \
    E0 = *(const float4*)&ea32[(size_t)se0.y * DE + l15 * 4];              \
    E1 = *(const float4*)&ea32[(size_t)se1.y * DE + l15 * 4];              \
  }
#define ESLOT(K, V, E, valid)                                              \
  {                                                                        \
    float dot = w0 * E.x + w1 * E.y + w2 * E.z + w3 * E.w;                 \
    _Pragma("unroll") for (int d = 0; d < 8; ++d)                          \
      dot = fmaf(q[d], bf2f((ushort)K[d]), dot);                           \
    dot += __shfl_xor(dot, 1);                                             \
    dot += __shfl_xor(dot, 2);                                             \
    dot += __shfl_xor(dot, 4);                                             \
    dot += __shfl_xor(dot, 8);                                             \
    float p = (valid) ? __expf(dot) : 0.f;                                 \
    s_acc += p;                                                            \
    _Pragma("unroll") for (int d = 0; d < 8; ++d)                          \
      av[d] = fmaf(p, bf2f((ushort)V[d]), av[d]);                          \
    ae[0] = fmaf(p, E.x, ae[0]); ae[1] = fmaf(p, E.y, ae[1]);              \
    ae[2] = fmaf(p, E.z, ae[2]); ae[3] = fmaf(p, E.w, ae[3]);              \
  }
#define ECOMP(K0, K1, V0, V1, E0, E1, base)                                \
  {                                                                        \
    ESLOT(K0, V0, E0, (base) + grp < end);                                 \
    ESLOT(K1, V1, E1, (base) + 4 + grp < end);                             \
  }

  if (beg < end) {
    bf16x8 kA0, kA1, vA0, vA1, kB0, kB1, vB0, vB1, kC0, kC1, vC0, vC1;
    float4 eA0, eA1, eB0, eB1, eC0, eC1;
    int iA = beg, iB = beg + 8, iC = beg + 16;
    ELOAD(kA0, kA1, vA0, vA1, eA0, eA1, iA);
    if (iB < end) ELOAD(kB0, kB1, vB0, vB1, eB0, eB1, iB);
    while (true) {
      if (iC < end) ELOAD(kC0, kC1, vC0, vC1, eC0, eC1, iC);
      ECOMP(kA0, kA1, vA0, vA1, eA0, eA1, iA);
      iA = iC + 8;
      if (iB >= end) break;
      if (iA < end) ELOAD(kA0, kA1, vA0, vA1, eA0, eA1, iA);
      ECOMP(kB0, kB1, vB0, vB1, eB0, eB1, iB);
      iB = iA + 8;
      if (iC >= end) break;
      if (iB < end) ELOAD(kB0, kB1, vB0, vB1, eB0, eB1, iB);
      ECOMP(kC0, kC1, vC0, vC1, eC0, eC1, iC);
      iC = iB + 8;
      if (iA >= end) break;
    }
  }
#undef ELOAD
#undef ESLOT
#undef ECOMP

  s_acc += __shfl_xor(s_acc, 16); s_acc += __shfl_xor(s_acc, 32);
  #pragma unroll
  for (int d = 0; d < 8; ++d) {
    av[d] += __shfl_xor(av[d], 16);
    av[d] += __shfl_xor(av[d], 32);
  }
  #pragma unroll
  for (int d = 0; d < 4; ++d) {
    ae[d] += __shfl_xor(ae[d], 16);
    ae[d] += __shfl_xor(ae[d], 32);
  }
  if (grp == 0) {
    if (l15 == 0) sden[n] = s_acc;
    float4 o0 = {av[0], av[1], av[2], av[3]};
    float4 o1 = {av[4], av[5], av[6], av[7]};
    float* vr = &vaccf[(size_t)n * 128 + l15 * 8];
    *(float4*)vr = o0;
    *(float4*)(vr + 4) = o1;
    ushort4 eo;
    eo.x = f2bf(ae[0]); eo.y = f2bf(ae[1]); eo.z = f2bf(ae[2]); eo.w = f2bf(ae[3]);
    *(ushort4*)&ewb[(size_t)n * DE + l15 * 4] = eo;
  }
}

// ---------- fused EWE GEMM + finalize via LDS ewout tile ----------
// phase A: ew = ewb @ We -> LDS [16][132] f32
// phase B: o = (vacc + ew)/s + hr, LN, ReLU -> ynorm (no atomics)
__global__ __launch_bounds__(256) void k_ewefin(const ushort* __restrict__ ewb,
                                                const ushort* __restrict__ Wp3,
                                                const float* __restrict__ sden,
                                                const float* __restrict__ vaccf,
                                                const ushort* __restrict__ hrb,
                                                const float* __restrict__ gamma,
                                                const float* __restrict__ beta,
                                                float* __restrict__ ynorm, int nN) {
  __shared__ float elds[16][132];
  int lane = threadIdx.x & 63, wave = threadIdx.x >> 6;
  int l15 = lane & 15, lh = lane >> 4;
  int m0 = blockIdx.x * 16;
  // ---- phase A ----
  {
    int rowa = m0 + l15; if (rowa >= nN) rowa = nN - 1;
    f32x4 acc[2] = {};
    #pragma unroll
    for (int s = 0; s < 2; ++s) {
      bf16x8 af = *(const bf16x8*)&ewb[(size_t)rowa * DE + s * 32 + lh * 8];
      #pragma unroll
      for (int tt = 0; tt < 2; ++tt) {
        int t = wave * 2 + tt;
        bf16x8 bf = *(const bf16x8*)&Wp3[((t * 2 + s) * 64 + lane) * 8];
        acc[tt] = __builtin_amdgcn_mfma_f32_16x16x32_bf16(af, bf, acc[tt], 0, 0, 0);
      }
    }
    #pragma unroll
    for (int tt = 0; tt < 2; ++tt) {
      int c = (wave * 2 + tt) * 16 + l15;
      #pragma unroll
      for (int r = 0; r < 4; ++r) elds[lh * 4 + r][c] = acc[tt][r];
    }
  }
  __syncthreads();
  // ---- phase B: 4 rows per wave (2 per 32-lane half, 2 iterations) ----
  int grp = lane >> 5, l5 = lane & 31;
  #pragma unroll
  for (int rr = 0; rr < 2; ++rr) {
    int rl = wave * 4 + rr * 2 + grp;
    int n = m0 + rl;
    if (n >= nN) continue;
    float s = sden[n];
    float inv = (s > 0.f) ? 1.f / s : 0.f;
    float4 v4 = *(const float4*)&vaccf[(size_t)n * 128 + l5 * 4];
    float4 w4 = *(const float4*)&elds[rl][l5 * 4];
    ushort4 hv = *(const ushort4*)&hrb[(size_t)n * 128 + l5 * 4];
    float4 o4;
    o4.x = (v4.x + w4.x) * inv + bf2f(hv.x);
    o4.y = (v4.y + w4.y) * inv + bf2f(hv.y);
    o4.z = (v4.z + w4.z) * inv + bf2f(hv.z);
    o4.w = (v4.w + w4.w) * inv + bf2f(hv.w);
    float s1 = o4.x + o4.y + o4.z + o4.w;
    float sq = o4.x*o4.x + o4.y*o4.y + o4.z*o4.z + o4.w*o4.w;
    #pragma unroll
    for (int off = 1; off < 32; off <<= 1) {
      s1 += __shfl_xor(s1, off);
      sq += __shfl_xor(sq, off);
    }
    float mu = s1 * (1.f / 128.f);
    float var = sq * (1.f / 128.f) - mu * mu;
    float rstd = rsqrtf(var + 1e-5f);
    float4 g4 = *(const float4*)&gamma[l5 * 4];
    float4 b4 = *(const float4*)&beta[l5 * 4];
    float4 y;
    y.x = fmaxf((o4.x - mu) * rstd * g4.x + b4.x, 0.f);
    y.y = fmaxf((o4.y - mu) * rstd * g4.y + b4.y, 0.f);
    y.z = fmaxf((o4.z - mu) * rstd * g4.z + b4.z, 0.f);
    y.w = fmaxf((o4.w - mu) * rstd * g4.w + b4.w, 0.f);
    *(float4*)&ynorm[(size_t)n * 128 + l5 * 4] = y;
  }
}

// ---------- segmented mean pool: one block per graph, contiguous node range ----------
__global__ __launch_bounds__(128) void k_pool(const float* __restrict__ ynorm,
                                              const int* __restrict__ gstart,
                                              float* __restrict__ out) {
  int b = blockIdx.x, t = threadIdx.x;
  int beg = gstart[b], end = gstart[b + 1];
  float a0 = 0.f, a1 = 0.f, a2 = 0.f, a3 = 0.f;
  int n = beg;
  for (; n + 4 <= end; n += 4) {
    a0 += ynorm[(size_t)(n + 0) * 128 + t];
    a1 += ynorm[(size_t)(n + 1) * 128 + t];
    a2 += ynorm[(size_t)(n + 2) * 128 + t];
    a3 += ynorm[(size_t)(n + 3) * 128 + t];
  }
  for (; n < end; ++n) a0 += ynorm[(size_t)n * 128 + t];
  float acc = (a0 + a1) + (a2 + a3);
  out[b * 128 + t] = acc / fmaxf((float)(end - beg), 1.f);
}

extern "C" void kernel_launch(void* const* d_in, const int* in_sizes, int n_in,
                              void* d_out, int out_size, void* d_ws, size_t ws_size,
                              hipStream_t stream) {
  const float* x         = (const float*)d_in[0];
  const float* edge_attr = (const float*)d_in[1];
  const int*   edge_index= (const int*)d_in[2];
  const int*   batch     = (const int*)d_in[3];
  const float* W1 = (const float*)d_in[4];
  const float* b1 = (const float*)d_in[5];
  const float* Wq = (const float*)d_in[6];  const float* bq = (const float*)d_in[7];
  const float* Wk = (const float*)d_in[8];  const float* bk = (const float*)d_in[9];
  const float* Wv = (const float*)d_in[10]; const float* bv = (const float*)d_in[11];
  const float* We = (const float*)d_in[12]; const float* be = (const float*)d_in[13];
  const float* Wr = (const float*)d_in[14]; const float* br = (const float*)d_in[15];
  const float* gamma = (const float*)d_in[16];
  const float* beta  = (const float*)d_in[17];
  float* out = (float*)d_out;

  const int nN = in_sizes[0] / DN;       // 50000
  const int nE = in_sizes[1] / DE;       // 1600000
  const int B  = out_size / DEMB;        // 64

  char* p = (char*)d_ws;
  auto alloc = [&](size_t bytes) -> void* {
    void* r = (void*)p;
    p += (bytes + 255) & ~(size_t)255;
    return r;
  };
  // ---- zeroed region ----
  int*   degi   = (int*)  alloc((size_t)nN * 4);
  int*   cursor = (int*)  alloc((size_t)nN * 4);
  size_t zero_bytes = (size_t)(p - (char*)d_ws);
  // ---- non-zeroed ----
  int*    row_ptr = (int*)   alloc((size_t)(nN + 1) * 4);
  int*    gstart  = (int*)   alloc((size_t)(B + 1) * 4);
  float*  dinv    = (float*) alloc((size_t)nN * 4);
  int2*   csr_se  = (int2*)  alloc((size_t)nE * 8);
  ushort* Wp1     = (ushort*)alloc((size_t)16 * 4 * 64 * 8 * 2);
  ushort* Wp2     = (ushort*)alloc((size_t)36 * 8 * 64 * 8 * 2);
  ushort* Wp3     = (ushort*)alloc((size_t)8 * 2 * 64 * 8 * 2);
  float*  bcat    = (float*) alloc(576 * 4);
  ushort* qwb     = (ushort*)alloc((size_t)nN * 192 * 2);
  ushort* hrb     = (ushort*)alloc((size_t)nN * 128 * 2);
  ushort* xsb     = (ushort*)alloc((size_t)nN * DN * 2);   // dead after k_gcnX
  ushort* aggxb   = (ushort*)alloc((size_t)nN * DN * 2);   // live through k_gemm12 phase A
  ushort* kvb     = (ushort*)alloc((size_t)nN * 256 * 2);  // own buffer (no overlay: gemm12 reads aggxb while writing kvb)
  float*  sden    = (float*) alloc((size_t)nN * 4);
  float*  vaccf   = (float*) alloc((size_t)nN * 128 * 4);
  ushort* ewb     = (ushort*)alloc((size_t)nN * DE * 2);
  float*  ynorm   = (float*) alloc((size_t)nN * 128 * 4);
  size_t required = (size_t)(p - (char*)d_ws);
  if (ws_size < required) return;

  hipMemsetAsync(d_ws, 0, zero_bytes, stream);

  k_prep_all<<<739, 256, 0, stream>>>(W1, Wq, Wk, Wv, Wr, We, bq, bk, bv, br, be,
                                      Wp1, Wp2, Wp3, bcat);
  k_deg<<<(nE + 255) / 256, 256, 0, stream>>>(edge_index, degi, nE);
  k_scan<<<1, 1024, 0, stream>>>(degi, row_ptr, dinv, nN);
  k_scatter<<<(nE + 255) / 256, 256, 0, stream>>>(edge_index, row_ptr, cursor,
                                                  csr_se, nE);
  k_xcast<<<(nN * 32 + 255) / 256, 256, 0, stream>>>(x, dinv, batch, gstart, xsb,
                                                     nN, B);
  k_gcnX<<<(nN + 3) / 4, 256, 0, stream>>>(xsb, csr_se, row_ptr, dinv, aggxb, nN);
  k_gemm12<<<(nN + 15) / 16, 256, 0, stream>>>(aggxb, Wp1, b1, Wp2, bcat,
                                               qwb, kvb, hrb, nN);
  k_edge<<<(nN + 3) / 4, 256, 0, stream>>>(qwb, kvb, edge_attr, csr_se, row_ptr,
                                           sden, vaccf, ewb, nN);
  k_ewefin<<<(nN + 15) / 16, 256, 0, stream>>>(ewb, Wp3, sden, vaccf, hrb,
                                               gamma, beta, ynorm, nN);
  k_pool<<<B, 128, 0, stream>>>(ynorm, gstart, out);
}

// Round 15
// 600.224 us; speedup vs baseline: 1.3779x; 1.3779x over previous
//
#include <hip/hip_runtime.h>

typedef short bf16x8 __attribute__((ext_vector_type(8)));
typedef float f32x4 __attribute__((ext_vector_type(4)));

#define DN 128
#define DE 64
#define DEMB 128
#define DHID 256
#define SCALE 0.08838834764831845f  // 1/sqrt(128)

__device__ __forceinline__ ushort f2bf(float f) {
  unsigned u = __float_as_uint(f);
  return (ushort)((u + 0x7FFFu + ((u >> 16) & 1u)) >> 16);  // RNE
}
__device__ __forceinline__ float bf2f(ushort u) {
  return __uint_as_float((unsigned)u << 16);
}

// ---------- fused weight prep: prep2 (576 blk) | prep1 (128) | prep3 (32) | prep_b (3) ----------
__global__ void k_prep_all(const float* __restrict__ W1, const float* __restrict__ Wq,
                           const float* __restrict__ Wk, const float* __restrict__ Wv,
                           const float* __restrict__ Wr, const float* __restrict__ We,
                           const float* __restrict__ bq, const float* __restrict__ bk,
                           const float* __restrict__ bv, const float* __restrict__ br,
                           const float* __restrict__ be,
                           ushort* __restrict__ Wp1, ushort* __restrict__ Wp2,
                           ushort* __restrict__ Wp3, float* __restrict__ bcat) {
  int bid = blockIdx.x;
  if (bid < 576) {
    int idx = bid * 256 + threadIdx.x;
    int j = idx & 7, lane = (idx >> 3) & 63, s = (idx >> 9) & 7, t = idx >> 12;
    int k = s * 32 + (lane >> 4) * 8 + j;
    int c = t * 16 + (lane & 15);
    float v;
    if (c < 128)       v = Wq[k * DEMB + c] * SCALE;
    else if (c < 256)  v = Wk[k * DEMB + (c - 128)];
    else if (c < 384)  v = Wv[k * DEMB + (c - 256)];
    else if (c < 512)  v = Wr[k * DEMB + (c - 384)];
    else {
      int cc = c - 512;
      float a = 0.f;
      for (int u = 0; u < DEMB; ++u) a += Wq[k * DEMB + u] * We[cc * DEMB + u];
      v = a * SCALE;
    }
    Wp2[idx] = f2bf(v);
  } else if (bid < 704) {
    int idx = (bid - 576) * 256 + threadIdx.x;
    int j = idx & 7, lane = (idx >> 3) & 63, s = (idx >> 9) & 3, t = idx >> 11;
    int k = s * 32 + (lane >> 4) * 8 + j;
    int c = t * 16 + (lane & 15);
    Wp1[idx] = f2bf(W1[k * DHID + c]);
  } else if (bid < 736) {
    int idx = (bid - 704) * 256 + threadIdx.x;
    int j = idx & 7, lane = (idx >> 3) & 63, s = (idx >> 9) & 1, t = idx >> 10;
    int k = s * 32 + (lane >> 4) * 8 + j;
    int c = t * 16 + (lane & 15);
    Wp3[idx] = f2bf(We[k * DEMB + c]);
  } else {
    int j = (bid - 736) * 256 + threadIdx.x;
    if (j >= 576) return;
    float v;
    if (j < 128)       v = bq[j] * SCALE;
    else if (j < 256)  v = bk[j - 128] + be[j - 128];
    else if (j < 384)  v = bv[j - 256] + be[j - 256];
    else if (j < 512)  v = br[j - 384];
    else {
      int cc = j - 512;
      float a = 0.f;
      for (int u = 0; u < DEMB; ++u) a += bq[u] * We[cc * DEMB + u];
      v = a * SCALE;
    }
    bcat[j] = v;
  }
}

// ---------- CSR build ----------
__global__ void k_deg(const int* __restrict__ ei, int* __restrict__ degi, int nE) {
  int e = blockIdx.x * 256 + threadIdx.x;
  if (e < nE) atomicAdd(&degi[ei[nE + e]], 1);
}

__global__ __launch_bounds__(1024) void k_scan(const int* __restrict__ degi,
                                               int* __restrict__ row_ptr,
                                               float* __restrict__ dinv, int n) {
  __shared__ int wsum[16];
  __shared__ int carry_s;
  int lane = threadIdx.x & 63, wid = threadIdx.x >> 6;
  if (threadIdx.x == 0) carry_s = 0;
  __syncthreads();
  for (int base = 0; base < n; base += 1024) {
    int i = base + threadIdx.x;
    int v = (i < n) ? degi[i] : 0;
    if (i < n) dinv[i] = rsqrtf(1.0f + (float)v);
    int sc = v;
    #pragma unroll
    for (int off = 1; off < 64; off <<= 1) {
      int t = __shfl_up(sc, off);
      if (lane >= off) sc += t;
    }
    if (lane == 63) wsum[wid] = sc;
    int carry0 = carry_s;
    __syncthreads();
    if (wid == 0) {
      int w = (lane < 16) ? wsum[lane] : 0;
      int swc = w;
      #pragma unroll
      for (int off = 1; off < 16; off <<= 1) {
        int t = __shfl_up(swc, off);
        if (lane >= off) swc += t;
      }
      if (lane < 16) wsum[lane] = swc - w;
      if (lane == 15) carry_s = carry0 + swc;
    }
    __syncthreads();
    if (i < n) row_ptr[i] = carry0 + wsum[wid] + sc - v;
    __syncthreads();
  }
  if (threadIdx.x == 0) row_ptr[n] = carry_s;
}

__global__ void k_scatter(const int* __restrict__ ei, const int* __restrict__ row_ptr,
                          int* __restrict__ cursor, int2* __restrict__ csr_se, int nE) {
  int e = blockIdx.x * 256 + threadIdx.x;
  if (e >= nE) return;
  int dst = ei[nE + e];
  int pos = row_ptr[dst] + atomicAdd(&cursor[dst], 1);
  csr_se[pos] = make_int2(ei[e], e);
}

// ---------- xcast (+ gbounds fused): xsb[n][128] = bf16(dinv[n]*x[n]) ----------
__global__ __launch_bounds__(256) void k_xcast(const float* __restrict__ x,
                                               const float* __restrict__ dinv,
                                               const int* __restrict__ batch,
                                               int* __restrict__ gstart,
                                               ushort* __restrict__ xsb, int nN, int B) {
  int idx = blockIdx.x * 256 + threadIdx.x;
  if (idx < nN) {
    int b = batch[idx];
    if (idx == 0) {
      for (int g = 0; g <= b; ++g) gstart[g] = 0;
    } else {
      int pb = batch[idx - 1];
      for (int g = pb + 1; g <= b; ++g) gstart[g] = idx;
    }
    if (idx == nN - 1) {
      for (int g = b + 1; g <= B; ++g) gstart[g] = nN;
    }
  }
  if (idx < nN * 32) {
    int n = idx >> 5, q = idx & 31;
    float dn = dinv[n];
    float4 v = *(const float4*)&x[(size_t)n * DN + q * 4];
    ushort4 o;
    o.x = f2bf(v.x * dn); o.y = f2bf(v.y * dn);
    o.z = f2bf(v.z * dn); o.w = f2bf(v.w * dn);
    *(ushort4*)&xsb[(size_t)n * DN + q * 4] = o;
  }
}

// ---------- GCN aggregate, ping-pong prefetch (R13, 617µs-verified): wave/node ----------
__global__ __launch_bounds__(256) void k_gcnX(const ushort* __restrict__ xsb,
                                              const int2* __restrict__ csr_se,
                                              const int* __restrict__ row_ptr,
                                              const float* __restrict__ dinv,
                                              ushort* __restrict__ aggxb, int nN) {
  int lane = threadIdx.x & 63;
  int n = blockIdx.x * 4 + (threadIdx.x >> 6);
  if (n >= nN) return;
  int grp = lane >> 4, l15 = lane & 15;
  int beg = row_ptr[n], end = row_ptr[n + 1];
  float acc[8] = {};

#define GLOAD(S0, S1, X0, X1, base)                                        \
  {                                                                        \
    int e0 = (base) + grp,     c0 = e0 < end ? e0 : end - 1;               \
    int e1 = (base) + 4 + grp, c1 = e1 < end ? e1 : end - 1;               \
    S0 = csr_se[c0].x; S1 = csr_se[c1].x;                                  \
    X0 = *(const uint4*)&xsb[(size_t)S0 * DN + l15 * 8];                   \
    X1 = *(const uint4*)&xsb[(size_t)S1 * DN + l15 * 8];                   \
  }
#define GCOMP(X0, X1, base)                                                \
  {                                                                        \
    float m0 = ((base) + grp < end) ? 1.f : 0.f;                           \
    float m1 = ((base) + 4 + grp < end) ? 1.f : 0.f;                       \
    unsigned q0[4] = {X0.x, X0.y, X0.z, X0.w};                             \
    unsigned q1[4] = {X1.x, X1.y, X1.z, X1.w};                             \
    _Pragma("unroll") for (int d = 0; d < 4; ++d) {                        \
      acc[2*d]   = fmaf(m0, __uint_as_float(q0[d] << 16), acc[2*d]);       \
      acc[2*d+1] = fmaf(m0, __uint_as_float(q0[d] & 0xFFFF0000u), acc[2*d+1]); \
      acc[2*d]   = fmaf(m1, __uint_as_float(q1[d] << 16), acc[2*d]);       \
      acc[2*d+1] = fmaf(m1, __uint_as_float(q1[d] & 0xFFFF0000u), acc[2*d+1]); \
    }                                                                      \
  }

  if (beg < end) {
    int sA0, sA1, sB0, sB1;
    uint4 xA0, xA1, xB0, xB1;
    int i0 = beg;
    GLOAD(sA0, sA1, xA0, xA1, i0);
    while (true) {
      int i1 = i0 + 8;
      if (i1 < end) GLOAD(sB0, sB1, xB0, xB1, i1);
      GCOMP(xA0, xA1, i0);
      i0 = i1;
      if (i0 >= end) break;
      int i2 = i0 + 8;
      if (i2 < end) GLOAD(sA0, sA1, xA0, xA1, i2);
      GCOMP(xB0, xB1, i0);
      i0 = i2;
      if (i0 >= end) break;
    }
  }
#undef GLOAD
#undef GCOMP

  #pragma unroll
  for (int d = 0; d < 8; ++d) {
    acc[d] += __shfl_xor(acc[d], 16);
    acc[d] += __shfl_xor(acc[d], 32);
  }
  if (grp == 0) {
    uint4 sa = *(const uint4*)&xsb[(size_t)n * DN + l15 * 8];
    unsigned sq[4] = {sa.x, sa.y, sa.z, sa.w};
    float dn = dinv[n];
    ushort o[8];
    #pragma unroll
    for (int d = 0; d < 4; ++d) {
      float lo = __uint_as_float(sq[d] << 16);
      float hi = __uint_as_float(sq[d] & 0xFFFF0000u);
      o[2*d]   = f2bf(dn * (acc[2*d]   + lo));
      o[2*d+1] = f2bf(dn * (acc[2*d+1] + hi));
    }
    uint4 ov = {(unsigned)o[0] | ((unsigned)o[1] << 16),
                (unsigned)o[2] | ((unsigned)o[3] << 16),
                (unsigned)o[4] | ((unsigned)o[5] << 16),
                (unsigned)o[6] | ((unsigned)o[7] << 16)};
    *(uint4*)&aggxb[(size_t)n * DN + l15 * 8] = ov;
  }
}

// ---------- fused GEMM1b+GEMM2 via LDS hb tile ----------
__global__ __launch_bounds__(256) void k_gemm12(const ushort* __restrict__ aggxb,
                                                const ushort* __restrict__ Wp1,
                                                const float* __restrict__ b1,
                                                const ushort* __restrict__ Wp2,
                                                const float* __restrict__ bcat,
                                                ushort* __restrict__ qwb,
                                                ushort* __restrict__ kvb,
                                                ushort* __restrict__ hrb, int nN) {
  __shared__ ushort hlds[16][264];
  int lane = threadIdx.x & 63, wave = threadIdx.x >> 6;
  int l15 = lane & 15, lh = lane >> 4;
  int m0 = blockIdx.x * 16;
  int rowa = m0 + l15; if (rowa >= nN) rowa = nN - 1;
  // ---- phase A ----
  {
    f32x4 acc[4] = {};
    #pragma unroll
    for (int s = 0; s < 4; ++s) {
      bf16x8 af = *(const bf16x8*)&aggxb[(size_t)rowa * DN + s * 32 + lh * 8];
      #pragma unroll
      for (int tt = 0; tt < 4; ++tt) {
        int t = wave * 4 + tt;
        bf16x8 bf = *(const bf16x8*)&Wp1[((t * 4 + s) * 64 + lane) * 8];
        acc[tt] = __builtin_amdgcn_mfma_f32_16x16x32_bf16(af, bf, acc[tt], 0, 0, 0);
      }
    }
    #pragma unroll
    for (int tt = 0; tt < 4; ++tt) {
      int c = (wave * 4 + tt) * 16 + l15;
      float bc = b1[c];
      #pragma unroll
      for (int r = 0; r < 4; ++r)
        hlds[lh * 4 + r][c] = f2bf(fmaxf(acc[tt][r] + bc, 0.f));
    }
  }
  __syncthreads();
  // ---- phase B ----
  {
    f32x4 acc[9] = {};
    for (int s = 0; s < 8; ++s) {
      bf16x8 af = *(const bf16x8*)&hlds[l15][s * 32 + lh * 8];
      #pragma unroll
      for (int tt = 0; tt < 9; ++tt) {
        int t = wave * 9 + tt;
        bf16x8 bf = *(const bf16x8*)&Wp2[((t * 8 + s) * 64 + lane) * 8];
        acc[tt] = __builtin_amdgcn_mfma_f32_16x16x32_bf16(af, bf, acc[tt], 0, 0, 0);
      }
    }
    #pragma unroll
    for (int tt = 0; tt < 9; ++tt) {
      int c = (wave * 9 + tt) * 16 + l15;
      float bc = bcat[c];
      #pragma unroll
      for (int r = 0; r < 4; ++r) {
        int row = m0 + lh * 4 + r;
        if (row >= nN) continue;
        ushort val = f2bf(acc[tt][r] + bc);
        if (c < 128)      qwb[(size_t)row * 192 + c] = val;
        else if (c < 256) { int d = c - 128; kvb[(size_t)row * 256 + (d >> 3) * 16 + (d & 7)] = val; }
        else if (c < 384) { int d = c - 256; kvb[(size_t)row * 256 + (d >> 3) * 16 + 8 + (d & 7)] = val; }
        else if (c < 512) hrb[(size_t)row * 128 + (c - 384)] = val;
        else              qwb[(size_t)row * 192 + 128 + (c - 512)] = val;
      }
    }
  }
}

// ---------- fused attention edge pass: ping-pong prefetch (R13, 617µs-verified) ----------
__global__ __launch_bounds__(256) void k_edge(const ushort* __restrict__ qwb,
                                              const ushort* __restrict__ kvb,
                                              const float* __restrict__ ea32,
                                              const int2* __restrict__ csr_se,
                                              const int* __restrict__ row_ptr,
                                              float* __restrict__ sden,
                                              float* __restrict__ vaccf,
                                              ushort* __restrict__ ewb, int nN) {
  int lane = threadIdx.x & 63;
  int n = blockIdx.x * 4 + (threadIdx.x >> 6);
  if (n >= nN) return;
  int grp = lane >> 4, l15 = lane & 15;
  const ushort* qp = &qwb[(size_t)n * 192];
  bf16x8 qv = *(const bf16x8*)&qp[l15 * 8];
  ushort4 wv = *(const ushort4*)&qp[128 + l15 * 4];
  float q[8];
  #pragma unroll
  for (int d = 0; d < 8; ++d) q[d] = bf2f((ushort)qv[d]);
  float w0 = bf2f(wv.x), w1 = bf2f(wv.y), w2 = bf2f(wv.z), w3 = bf2f(wv.w);
  float s_acc = 0.f;
  float av[8] = {};
  float ae[4] = {};
  int beg = row_ptr[n], end = row_ptr[n + 1];

#define ELOAD(SE0, SE1, K0, K1, V0, V1, E0, E1, base)                      \
  {                                                                        \
    int e0 = (base) + grp,     c0 = e0 < end ? e0 : end - 1;               \
    int e1 = (base) + 4 + grp, c1 = e1 < end ? e1 : end - 1;               \
    SE0 = csr_se[c0]; SE1 = csr_se[c1];                                    \
    const ushort* r0 = &kvb[(size_t)SE0.x * 256 + l15 * 16];               \
    const ushort* r1 = &kvb[(size_t)SE1.x * 256 + l15 * 16];               \
    K0 = *(const bf16x8*)r0;  V0 = *(const bf16x8*)(r0 + 8);               \
    K1 = *(const bf16x8*)r1;  V1 = *(const bf16x8*)(r1 + 8);               \
    E0 = *(const float4*)&ea32[(size_t)SE0.y * DE + l15 * 4];              \
    E1 = *(const float4*)&ea32[(size_t)SE1.y * DE + l15 * 4];              \
  }
#define ESLOT(K, V, E, valid)                                              \
  {                                                                        \
    float dot = w0 * E.x + w1 * E.y + w2 * E.z + w3 * E.w;                 \
    _Pragma("unroll") for (int d = 0; d < 8; ++d)                          \
      dot = fmaf(q[d], bf2f((ushort)K[d]), dot);                           \
    dot += __shfl_xor(dot, 1);                                             \
    dot += __shfl_xor(dot, 2);                                             \
    dot += __shfl_xor(dot, 4);                                             \
    dot += __shfl_xor(dot, 8);                                             \
    float p = (valid) ? __expf(dot) : 0.f;                                 \
    s_acc += p;                                                            \
    _Pragma("unroll") for (int d = 0; d < 8; ++d)                          \
      av[d] = fmaf(p, bf2f((ushort)V[d]), av[d]);                          \
    ae[0] = fmaf(p, E.x, ae[0]); ae[1] = fmaf(p, E.y, ae[1]);              \
    ae[2] = fmaf(p, E.z, ae[2]); ae[3] = fmaf(p, E.w, ae[3]);              \
  }
#define ECOMP(K0, K1, V0, V1, E0, E1, base)                                \
  {                                                                        \
    ESLOT(K0, V0, E0, (base) + grp < end);                                 \
    ESLOT(K1, V1, E1, (base) + 4 + grp < end);                             \
  }

  if (beg < end) {
    int2 seA0, seA1, seB0, seB1;
    bf16x8 kA0, kA1, vA0, vA1, kB0, kB1, vB0, vB1;
    float4 eA0, eA1, eB0, eB1;
    int i0 = beg;
    ELOAD(seA0, seA1, kA0, kA1, vA0, vA1, eA0, eA1, i0);
    while (true) {
      int i1 = i0 + 8;
      if (i1 < end) ELOAD(seB0, seB1, kB0, kB1, vB0, vB1, eB0, eB1, i1);
      ECOMP(kA0, kA1, vA0, vA1, eA0, eA1, i0);
      i0 = i1;
      if (i0 >= end) break;
      int i2 = i0 + 8;
      if (i2 < end) ELOAD(seA0, seA1, kA0, kA1, vA0, vA1, eA0, eA1, i2);
      ECOMP(kB0, kB1, vB0, vB1, eB0, eB1, i0);
      i0 = i2;
      if (i0 >= end) break;
    }
  }
#undef ELOAD
#undef ESLOT
#undef ECOMP

  s_acc += __shfl_xor(s_acc, 16); s_acc += __shfl_xor(s_acc, 32);
  #pragma unroll
  for (int d = 0; d < 8; ++d) {
    av[d] += __shfl_xor(av[d], 16);
    av[d] += __shfl_xor(av[d], 32);
  }
  #pragma unroll
  for (int d = 0; d < 4; ++d) {
    ae[d] += __shfl_xor(ae[d], 16);
    ae[d] += __shfl_xor(ae[d], 32);
  }
  if (grp == 0) {
    if (l15 == 0) sden[n] = s_acc;
    float4 o0 = {av[0], av[1], av[2], av[3]};
    float4 o1 = {av[4], av[5], av[6], av[7]};
    float* vr = &vaccf[(size_t)n * 128 + l15 * 8];
    *(float4*)vr = o0;
    *(float4*)(vr + 4) = o1;
    ushort4 eo;
    eo.x = f2bf(ae[0]); eo.y = f2bf(ae[1]); eo.z = f2bf(ae[2]); eo.w = f2bf(ae[3]);
    *(ushort4*)&ewb[(size_t)n * DE + l15 * 4] = eo;
  }
}

// ---------- fused EWE GEMM + finalize via LDS ewout tile ----------
__global__ __launch_bounds__(256) void k_ewefin(const ushort* __restrict__ ewb,
                                                const ushort* __restrict__ Wp3,
                                                const float* __restrict__ sden,
                                                const float* __restrict__ vaccf,
                                                const ushort* __restrict__ hrb,
                                                const float* __restrict__ gamma,
                                                const float* __restrict__ beta,
                                                float* __restrict__ ynorm, int nN) {
  __shared__ float elds[16][132];
  int lane = threadIdx.x & 63, wave = threadIdx.x >> 6;
  int l15 = lane & 15, lh = lane >> 4;
  int m0 = blockIdx.x * 16;
  // ---- phase A ----
  {
    int rowa = m0 + l15; if (rowa >= nN) rowa = nN - 1;
    f32x4 acc[2] = {};
    #pragma unroll
    for (int s = 0; s < 2; ++s) {
      bf16x8 af = *(const bf16x8*)&ewb[(size_t)rowa * DE + s * 32 + lh * 8];
      #pragma unroll
      for (int tt = 0; tt < 2; ++tt) {
        int t = wave * 2 + tt;
        bf16x8 bf = *(const bf16x8*)&Wp3[((t * 2 + s) * 64 + lane) * 8];
        acc[tt] = __builtin_amdgcn_mfma_f32_16x16x32_bf16(af, bf, acc[tt], 0, 0, 0);
      }
    }
    #pragma unroll
    for (int tt = 0; tt < 2; ++tt) {
      int c = (wave * 2 + tt) * 16 + l15;
      #pragma unroll
      for (int r = 0; r < 4; ++r) elds[lh * 4 + r][c] = acc[tt][r];
    }
  }
  __syncthreads();
  // ---- phase B: 4 rows per wave ----
  int grp = lane >> 5, l5 = lane & 31;
  #pragma unroll
  for (int rr = 0; rr < 2; ++rr) {
    int rl = wave * 4 + rr * 2 + grp;
    int n = m0 + rl;
    if (n >= nN) continue;
    float s = sden[n];
    float inv = (s > 0.f) ? 1.f / s : 0.f;
    float4 v4 = *(const float4*)&vaccf[(size_t)n * 128 + l5 * 4];
    float4 w4 = *(const float4*)&elds[rl][l5 * 4];
    ushort4 hv = *(const ushort4*)&hrb[(size_t)n * 128 + l5 * 4];
    float4 o4;
    o4.x = (v4.x + w4.x) * inv + bf2f(hv.x);
    o4.y = (v4.y + w4.y) * inv + bf2f(hv.y);
    o4.z = (v4.z + w4.z) * inv + bf2f(hv.z);
    o4.w = (v4.w + w4.w) * inv + bf2f(hv.w);
    float s1 = o4.x + o4.y + o4.z + o4.w;
    float sq = o4.x*o4.x + o4.y*o4.y + o4.z*o4.z + o4.w*o4.w;
    #pragma unroll
    for (int off = 1; off < 32; off <<= 1) {
      s1 += __shfl_xor(s1, off);
      sq += __shfl_xor(sq, off);
    }
    float mu = s1 * (1.f / 128.f);
    float var = sq * (1.f / 128.f) - mu * mu;
    float rstd = rsqrtf(var + 1e-5f);
    float4 g4 = *(const float4*)&gamma[l5 * 4];
    float4 b4 = *(const float4*)&beta[l5 * 4];
    float4 y;
    y.x = fmaxf((o4.x - mu) * rstd * g4.x + b4.x, 0.f);
    y.y = fmaxf((o4.y - mu) * rstd * g4.y + b4.y, 0.f);
    y.z = fmaxf((o4.z - mu) * rstd * g4.z + b4.z, 0.f);
    y.w = fmaxf((o4.w - mu) * rstd * g4.w + b4.w, 0.f);
    *(float4*)&ynorm[(size_t)n * 128 + l5 * 4] = y;
  }
}

// ---------- segmented mean pool: one block per graph, contiguous node range ----------
__global__ __launch_bounds__(128) void k_pool(const float* __restrict__ ynorm,
                                              const int* __restrict__ gstart,
                                              float* __restrict__ out) {
  int b = blockIdx.x, t = threadIdx.x;
  int beg = gstart[b], end = gstart[b + 1];
  float a0 = 0.f, a1 = 0.f, a2 = 0.f, a3 = 0.f;
  int n = beg;
  for (; n + 4 <= end; n += 4) {
    a0 += ynorm[(size_t)(n + 0) * 128 + t];
    a1 += ynorm[(size_t)(n + 1) * 128 + t];
    a2 += ynorm[(size_t)(n + 2) * 128 + t];
    a3 += ynorm[(size_t)(n + 3) * 128 + t];
  }
  for (; n < end; ++n) a0 += ynorm[(size_t)n * 128 + t];
  float acc = (a0 + a1) + (a2 + a3);
  out[b * 128 + t] = acc / fmaxf((float)(end - beg), 1.f);
}

extern "C" void kernel_launch(void* const* d_in, const int* in_sizes, int n_in,
                              void* d_out, int out_size, void* d_ws, size_t ws_size,
                              hipStream_t stream) {
  const float* x         = (const float*)d_in[0];
  const float* edge_attr = (const float*)d_in[1];
  const int*   edge_index= (const int*)d_in[2];
  const int*   batch     = (const int*)d_in[3];
  const float* W1 = (const float*)d_in[4];
  const float* b1 = (const float*)d_in[5];
  const float* Wq = (const float*)d_in[6];  const float* bq = (const float*)d_in[7];
  const float* Wk = (const float*)d_in[8];  const float* bk = (const float*)d_in[9];
  const float* Wv = (const float*)d_in[10]; const float* bv = (const float*)d_in[11];
  const float* We = (const float*)d_in[12]; const float* be = (const float*)d_in[13];
  const float* Wr = (const float*)d_in[14]; const float* br = (const float*)d_in[15];
  const float* gamma = (const float*)d_in[16];
  const float* beta  = (const float*)d_in[17];
  float* out = (float*)d_out;

  const int nN = in_sizes[0] / DN;       // 50000
  const int nE = in_sizes[1] / DE;       // 1600000
  const int B  = out_size / DEMB;        // 64

  char* p = (char*)d_ws;
  auto alloc = [&](size_t bytes) -> void* {
    void* r = (void*)p;
    p += (bytes + 255) & ~(size_t)255;
    return r;
  };
  // ---- zeroed region ----
  int*   degi   = (int*)  alloc((size_t)nN * 4);
  int*   cursor = (int*)  alloc((size_t)nN * 4);
  size_t zero_bytes = (size_t)(p - (char*)d_ws);
  // ---- non-zeroed ----
  int*    row_ptr = (int*)   alloc((size_t)(nN + 1) * 4);
  int*    gstart  = (int*)   alloc((size_t)(B + 1) * 4);
  float*  dinv    = (float*) alloc((size_t)nN * 4);
  int2*   csr_se  = (int2*)  alloc((size_t)nE * 8);
  ushort* Wp1     = (ushort*)alloc((size_t)16 * 4 * 64 * 8 * 2);
  ushort* Wp2     = (ushort*)alloc((size_t)36 * 8 * 64 * 8 * 2);
  ushort* Wp3     = (ushort*)alloc((size_t)8 * 2 * 64 * 8 * 2);
  float*  bcat    = (float*) alloc(576 * 4);
  ushort* qwb     = (ushort*)alloc((size_t)nN * 192 * 2);
  ushort* hrb     = (ushort*)alloc((size_t)nN * 128 * 2);
  ushort* xsb     = (ushort*)alloc((size_t)nN * DN * 2);   // dead after k_gcnX
  ushort* aggxb   = (ushort*)alloc((size_t)nN * DN * 2);   // live through k_gemm12 phase A
  ushort* kvb     = (ushort*)alloc((size_t)nN * 256 * 2);  // own buffer (gemm12 reads aggxb while writing kvb)
  float*  sden    = (float*) alloc((size_t)nN * 4);
  float*  vaccf   = (float*) alloc((size_t)nN * 128 * 4);
  ushort* ewb     = (ushort*)alloc((size_t)nN * DE * 2);
  float*  ynorm   = (float*) alloc((size_t)nN * 128 * 4);
  size_t required = (size_t)(p - (char*)d_ws);
  if (ws_size < required) return;

  hipMemsetAsync(d_ws, 0, zero_bytes, stream);

  k_prep_all<<<739, 256, 0, stream>>>(W1, Wq, Wk, Wv, Wr, We, bq, bk, bv, br, be,
                                      Wp1, Wp2, Wp3, bcat);
  k_deg<<<(nE + 255) / 256, 256, 0, stream>>>(edge_index, degi, nE);
  k_scan<<<1, 1024, 0, stream>>>(degi, row_ptr, dinv, nN);
  k_scatter<<<(nE + 255) / 256, 256, 0, stream>>>(edge_index, row_ptr, cursor,
                                                  csr_se, nE);
  k_xcast<<<(nN * 32 + 255) / 256, 256, 0, stream>>>(x, dinv, batch, gstart, xsb,
                                                     nN, B);
  k_gcnX<<<(nN + 3) / 4, 256, 0, stream>>>(xsb, csr_se, row_ptr, dinv, aggxb, nN);
  k_gemm12<<<(nN + 15) / 16, 256, 0, stream>>>(aggxb, Wp1, b1, Wp2, bcat,
                                               qwb, kvb, hrb, nN);
  k_edge<<<(nN + 3) / 4, 256, 0, stream>>>(qwb, kvb, edge_attr, csr_se, row_ptr,
                                           sden, vaccf, ewb, nN);
  k_ewefin<<<(nN + 15) / 16, 256, 0, stream>>>(ewb, Wp3, sden, vaccf, hrb,
                                               gamma, beta, ynorm, nN);
  k_pool<<<B, 128, 0, stream>>>(ynorm, gstart, out);
}

// Round 16
// 587.825 us; speedup vs baseline: 1.4069x; 1.0211x over previous
//
#include <hip/hip_runtime.h>

typedef short bf16x8 __attribute__((ext_vector_type(8)));
typedef float f32x4 __attribute__((ext_vector_type(4)));

#define DN 128
#define DE 64
#define DEMB 128
#define DHID 256
#define SCALE 0.08838834764831845f  // 1/sqrt(128)

__device__ __forceinline__ ushort f2bf(float f) {
  unsigned u = __float_as_uint(f);
  return (ushort)((u + 0x7FFFu + ((u >> 16) & 1u)) >> 16);  // RNE
}
__device__ __forceinline__ float bf2f(ushort u) {
  return __uint_as_float((unsigned)u << 16);
}

// ---------- fused weight prep: prep2 (576 blk) | prep1 (128) | prep3 (32) | prep_b (3) ----------
__global__ void k_prep_all(const float* __restrict__ W1, const float* __restrict__ Wq,
                           const float* __restrict__ Wk, const float* __restrict__ Wv,
                           const float* __restrict__ Wr, const float* __restrict__ We,
                           const float* __restrict__ bq, const float* __restrict__ bk,
                           const float* __restrict__ bv, const float* __restrict__ br,
                           const float* __restrict__ be,
                           ushort* __restrict__ Wp1, ushort* __restrict__ Wp2,
                           ushort* __restrict__ Wp3, float* __restrict__ bcat) {
  int bid = blockIdx.x;
  if (bid < 576) {
    int idx = bid * 256 + threadIdx.x;
    int j = idx & 7, lane = (idx >> 3) & 63, s = (idx >> 9) & 7, t = idx >> 12;
    int k = s * 32 + (lane >> 4) * 8 + j;
    int c = t * 16 + (lane & 15);
    float v;
    if (c < 128)       v = Wq[k * DEMB + c] * SCALE;
    else if (c < 256)  v = Wk[k * DEMB + (c - 128)];
    else if (c < 384)  v = Wv[k * DEMB + (c - 256)];
    else if (c < 512)  v = Wr[k * DEMB + (c - 384)];
    else {
      int cc = c - 512;
      float a = 0.f;
      for (int u = 0; u < DEMB; ++u) a += Wq[k * DEMB + u] * We[cc * DEMB + u];
      v = a * SCALE;
    }
    Wp2[idx] = f2bf(v);
  } else if (bid < 704) {
    int idx = (bid - 576) * 256 + threadIdx.x;
    int j = idx & 7, lane = (idx >> 3) & 63, s = (idx >> 9) & 3, t = idx >> 11;
    int k = s * 32 + (lane >> 4) * 8 + j;
    int c = t * 16 + (lane & 15);
    Wp1[idx] = f2bf(W1[k * DHID + c]);
  } else if (bid < 736) {
    int idx = (bid - 704) * 256 + threadIdx.x;
    int j = idx & 7, lane = (idx >> 3) & 63, s = (idx >> 9) & 1, t = idx >> 10;
    int k = s * 32 + (lane >> 4) * 8 + j;
    int c = t * 16 + (lane & 15);
    Wp3[idx] = f2bf(We[k * DEMB + c]);
  } else {
    int j = (bid - 736) * 256 + threadIdx.x;
    if (j >= 576) return;
    float v;
    if (j < 128)       v = bq[j] * SCALE;
    else if (j < 256)  v = bk[j - 128] + be[j - 128];
    else if (j < 384)  v = bv[j - 256] + be[j - 256];
    else if (j < 512)  v = br[j - 384];
    else {
      int cc = j - 512;
      float a = 0.f;
      for (int u = 0; u < DEMB; ++u) a += bq[u] * We[cc * DEMB + u];
      v = a * SCALE;
    }
    bcat[j] = v;
  }
}

// ---------- CSR build ----------
__global__ void k_deg(const int* __restrict__ ei, int* __restrict__ degi, int nE) {
  int e = blockIdx.x * 256 + threadIdx.x;
  if (e < nE) atomicAdd(&degi[ei[nE + e]], 1);
}

__global__ __launch_bounds__(1024) void k_scan(const int* __restrict__ degi,
                                               int* __restrict__ row_ptr,
                                               float* __restrict__ dinv, int n) {
  __shared__ int wsum[16];
  __shared__ int carry_s;
  int lane = threadIdx.x & 63, wid = threadIdx.x >> 6;
  if (threadIdx.x == 0) carry_s = 0;
  __syncthreads();
  for (int base = 0; base < n; base += 1024) {
    int i = base + threadIdx.x;
    int v = (i < n) ? degi[i] : 0;
    if (i < n) dinv[i] = rsqrtf(1.0f + (float)v);
    int sc = v;
    #pragma unroll
    for (int off = 1; off < 64; off <<= 1) {
      int t = __shfl_up(sc, off);
      if (lane >= off) sc += t;
    }
    if (lane == 63) wsum[wid] = sc;
    int carry0 = carry_s;
    __syncthreads();
    if (wid == 0) {
      int w = (lane < 16) ? wsum[lane] : 0;
      int swc = w;
      #pragma unroll
      for (int off = 1; off < 16; off <<= 1) {
        int t = __shfl_up(swc, off);
        if (lane >= off) swc += t;
      }
      if (lane < 16) wsum[lane] = swc - w;
      if (lane == 15) carry_s = carry0 + swc;
    }
    __syncthreads();
    if (i < n) row_ptr[i] = carry0 + wsum[wid] + sc - v;
    __syncthreads();
  }
  if (threadIdx.x == 0) row_ptr[n] = carry_s;
}

__global__ void k_scatter(const int* __restrict__ ei, const int* __restrict__ row_ptr,
                          int* __restrict__ cursor, int2* __restrict__ csr_se, int nE) {
  int e = blockIdx.x * 256 + threadIdx.x;
  if (e >= nE) return;
  int dst = ei[nE + e];
  int pos = row_ptr[dst] + atomicAdd(&cursor[dst], 1);
  csr_se[pos] = make_int2(ei[e], e);
}

// ---------- xcast (+ gbounds fused): xsb[n][128] = bf16(dinv[n]*x[n]) ----------
__global__ __launch_bounds__(256) void k_xcast(const float* __restrict__ x,
                                               const float* __restrict__ dinv,
                                               const int* __restrict__ batch,
                                               int* __restrict__ gstart,
                                               ushort* __restrict__ xsb, int nN, int B) {
  int idx = blockIdx.x * 256 + threadIdx.x;
  if (idx < nN) {
    int b = batch[idx];
    if (idx == 0) {
      for (int g = 0; g <= b; ++g) gstart[g] = 0;
    } else {
      int pb = batch[idx - 1];
      for (int g = pb + 1; g <= b; ++g) gstart[g] = idx;
    }
    if (idx == nN - 1) {
      for (int g = b + 1; g <= B; ++g) gstart[g] = nN;
    }
  }
  if (idx < nN * 32) {
    int n = idx >> 5, q = idx & 31;
    float dn = dinv[n];
    float4 v = *(const float4*)&x[(size_t)n * DN + q * 4];
    ushort4 o;
    o.x = f2bf(v.x * dn); o.y = f2bf(v.y * dn);
    o.z = f2bf(v.z * dn); o.w = f2bf(v.w * dn);
    *(ushort4*)&xsb[(size_t)n * DN + q * 4] = o;
  }
}

// ---------- GCN aggregate: bulk index preload (64 edges/coalesced load) + ping-pong ----------
__global__ __launch_bounds__(256) void k_gcnX(const ushort* __restrict__ xsb,
                                              const int2* __restrict__ csr_se,
                                              const int* __restrict__ row_ptr,
                                              const float* __restrict__ dinv,
                                              ushort* __restrict__ aggxb, int nN) {
  int lane = threadIdx.x & 63;
  int n = blockIdx.x * 4 + (threadIdx.x >> 6);
  if (n >= nN) return;
  int grp = lane >> 4, l15 = lane & 15;
  int beg = row_ptr[n], end = row_ptr[n + 1];
  float acc[8] = {};

  for (int w0 = beg; w0 < end; w0 += 64) {
    int wend = w0 + 64 < end ? w0 + 64 : end;
    int li = w0 + lane; if (li >= end) li = end - 1;
    int sidx = csr_se[li].x;                     // 64 edges of src per wave, coalesced

#define GLOAD(X0, X1, base)                                                \
  {                                                                        \
    int c0 = (base) + grp;     if (c0 >= wend) c0 = wend - 1;              \
    int c1 = (base) + 4 + grp; if (c1 >= wend) c1 = wend - 1;              \
    int s0 = __shfl(sidx, c0 - w0);                                        \
    int s1 = __shfl(sidx, c1 - w0);                                        \
    X0 = *(const uint4*)&xsb[(size_t)s0 * DN + l15 * 8];                   \
    X1 = *(const uint4*)&xsb[(size_t)s1 * DN + l15 * 8];                   \
  }
#define GCOMP(X0, X1, base)                                                \
  {                                                                        \
    float m0 = ((base) + grp < end) ? 1.f : 0.f;                           \
    float m1 = ((base) + 4 + grp < end) ? 1.f : 0.f;                       \
    unsigned q0[4] = {X0.x, X0.y, X0.z, X0.w};                             \
    unsigned q1[4] = {X1.x, X1.y, X1.z, X1.w};                             \
    _Pragma("unroll") for (int d = 0; d < 4; ++d) {                        \
      acc[2*d]   = fmaf(m0, __uint_as_float(q0[d] << 16), acc[2*d]);       \
      acc[2*d+1] = fmaf(m0, __uint_as_float(q0[d] & 0xFFFF0000u), acc[2*d+1]); \
      acc[2*d]   = fmaf(m1, __uint_as_float(q1[d] << 16), acc[2*d]);       \
      acc[2*d+1] = fmaf(m1, __uint_as_float(q1[d] & 0xFFFF0000u), acc[2*d+1]); \
    }                                                                      \
  }

    uint4 xA0, xA1, xB0, xB1;
    int i0 = w0;
    GLOAD(xA0, xA1, i0);
    while (true) {
      int i1 = i0 + 8;
      if (i1 < wend) GLOAD(xB0, xB1, i1);
      GCOMP(xA0, xA1, i0);
      i0 = i1;
      if (i0 >= wend) break;
      int i2 = i0 + 8;
      if (i2 < wend) GLOAD(xA0, xA1, i2);
      GCOMP(xB0, xB1, i0);
      i0 = i2;
      if (i0 >= wend) break;
    }
#undef GLOAD
#undef GCOMP
  }

  #pragma unroll
  for (int d = 0; d < 8; ++d) {
    acc[d] += __shfl_xor(acc[d], 16);
    acc[d] += __shfl_xor(acc[d], 32);
  }
  if (grp == 0) {
    uint4 sa = *(const uint4*)&xsb[(size_t)n * DN + l15 * 8];
    unsigned sq[4] = {sa.x, sa.y, sa.z, sa.w};
    float dn = dinv[n];
    ushort o[8];
    #pragma unroll
    for (int d = 0; d < 4; ++d) {
      float lo = __uint_as_float(sq[d] << 16);
      float hi = __uint_as_float(sq[d] & 0xFFFF0000u);
      o[2*d]   = f2bf(dn * (acc[2*d]   + lo));
      o[2*d+1] = f2bf(dn * (acc[2*d+1] + hi));
    }
    uint4 ov = {(unsigned)o[0] | ((unsigned)o[1] << 16),
                (unsigned)o[2] | ((unsigned)o[3] << 16),
                (unsigned)o[4] | ((unsigned)o[5] << 16),
                (unsigned)o[6] | ((unsigned)o[7] << 16)};
    *(uint4*)&aggxb[(size_t)n * DN + l15 * 8] = ov;
  }
}

// ---------- fused GEMM1b+GEMM2 via LDS hb tile ----------
__global__ __launch_bounds__(256) void k_gemm12(const ushort* __restrict__ aggxb,
                                                const ushort* __restrict__ Wp1,
                                                const float* __restrict__ b1,
                                                const ushort* __restrict__ Wp2,
                                                const float* __restrict__ bcat,
                                                ushort* __restrict__ qwb,
                                                ushort* __restrict__ kvb,
                                                ushort* __restrict__ hrb, int nN) {
  __shared__ ushort hlds[16][264];
  int lane = threadIdx.x & 63, wave = threadIdx.x >> 6;
  int l15 = lane & 15, lh = lane >> 4;
  int m0 = blockIdx.x * 16;
  int rowa = m0 + l15; if (rowa >= nN) rowa = nN - 1;
  // ---- phase A ----
  {
    f32x4 acc[4] = {};
    #pragma unroll
    for (int s = 0; s < 4; ++s) {
      bf16x8 af = *(const bf16x8*)&aggxb[(size_t)rowa * DN + s * 32 + lh * 8];
      #pragma unroll
      for (int tt = 0; tt < 4; ++tt) {
        int t = wave * 4 + tt;
        bf16x8 bf = *(const bf16x8*)&Wp1[((t * 4 + s) * 64 + lane) * 8];
        acc[tt] = __builtin_amdgcn_mfma_f32_16x16x32_bf16(af, bf, acc[tt], 0, 0, 0);
      }
    }
    #pragma unroll
    for (int tt = 0; tt < 4; ++tt) {
      int c = (wave * 4 + tt) * 16 + l15;
      float bc = b1[c];
      #pragma unroll
      for (int r = 0; r < 4; ++r)
        hlds[lh * 4 + r][c] = f2bf(fmaxf(acc[tt][r] + bc, 0.f));
    }
  }
  __syncthreads();
  // ---- phase B ----
  {
    f32x4 acc[9] = {};
    for (int s = 0; s < 8; ++s) {
      bf16x8 af = *(const bf16x8*)&hlds[l15][s * 32 + lh * 8];
      #pragma unroll
      for (int tt = 0; tt < 9; ++tt) {
        int t = wave * 9 + tt;
        bf16x8 bf = *(const bf16x8*)&Wp2[((t * 8 + s) * 64 + lane) * 8];
        acc[tt] = __builtin_amdgcn_mfma_f32_16x16x32_bf16(af, bf, acc[tt], 0, 0, 0);
      }
    }
    #pragma unroll
    for (int tt = 0; tt < 9; ++tt) {
      int c = (wave * 9 + tt) * 16 + l15;
      float bc = bcat[c];
      #pragma unroll
      for (int r = 0; r < 4; ++r) {
        int row = m0 + lh * 4 + r;
        if (row >= nN) continue;
        ushort val = f2bf(acc[tt][r] + bc);
        if (c < 128)      qwb[(size_t)row * 192 + c] = val;
        else if (c < 256) { int d = c - 128; kvb[(size_t)row * 256 + (d >> 3) * 16 + (d & 7)] = val; }
        else if (c < 384) { int d = c - 256; kvb[(size_t)row * 256 + (d >> 3) * 16 + 8 + (d & 7)] = val; }
        else if (c < 512) hrb[(size_t)row * 128 + (c - 384)] = val;
        else              qwb[(size_t)row * 192 + 128 + (c - 512)] = val;
      }
    }
  }
}

// ---------- fused attention edge pass: bulk index preload + ping-pong prefetch ----------
__global__ __launch_bounds__(256) void k_edge(const ushort* __restrict__ qwb,
                                              const ushort* __restrict__ kvb,
                                              const float* __restrict__ ea32,
                                              const int2* __restrict__ csr_se,
                                              const int* __restrict__ row_ptr,
                                              float* __restrict__ sden,
                                              float* __restrict__ vaccf,
                                              ushort* __restrict__ ewb, int nN) {
  int lane = threadIdx.x & 63;
  int n = blockIdx.x * 4 + (threadIdx.x >> 6);
  if (n >= nN) return;
  int grp = lane >> 4, l15 = lane & 15;
  const ushort* qp = &qwb[(size_t)n * 192];
  bf16x8 qv = *(const bf16x8*)&qp[l15 * 8];
  ushort4 wv = *(const ushort4*)&qp[128 + l15 * 4];
  float q[8];
  #pragma unroll
  for (int d = 0; d < 8; ++d) q[d] = bf2f((ushort)qv[d]);
  float w0 = bf2f(wv.x), w1 = bf2f(wv.y), w2 = bf2f(wv.z), w3 = bf2f(wv.w);
  float s_acc = 0.f;
  float av[8] = {};
  float ae[4] = {};
  int beg = row_ptr[n], end = row_ptr[n + 1];

  for (int wnd = beg; wnd < end; wnd += 64) {
    int wend = wnd + 64 < end ? wnd + 64 : end;
    int li = wnd + lane; if (li >= end) li = end - 1;
    int2 sidx = csr_se[li];                      // 64 edges of (src,eid), coalesced

#define ELOAD(K0, K1, V0, V1, E0, E1, base)                                \
  {                                                                        \
    int c0 = (base) + grp;     if (c0 >= wend) c0 = wend - 1;              \
    int c1 = (base) + 4 + grp; if (c1 >= wend) c1 = wend - 1;              \
    int sx0 = __shfl(sidx.x, c0 - wnd), sy0 = __shfl(sidx.y, c0 - wnd);    \
    int sx1 = __shfl(sidx.x, c1 - wnd), sy1 = __shfl(sidx.y, c1 - wnd);    \
    const ushort* r0 = &kvb[(size_t)sx0 * 256 + l15 * 16];                 \
    const ushort* r1 = &kvb[(size_t)sx1 * 256 + l15 * 16];                 \
    K0 = *(const bf16x8*)r0;  V0 = *(const bf16x8*)(r0 + 8);               \
    K1 = *(const bf16x8*)r1;  V1 = *(const bf16x8*)(r1 + 8);               \
    E0 = *(const float4*)&ea32[(size_t)sy0 * DE + l15 * 4];                \
    E1 = *(const float4*)&ea32[(size_t)sy1 * DE + l15 * 4];                \
  }
#define ESLOT(K, V, E, valid)                                              \
  {                                                                        \
    float dot = w0 * E.x + w1 * E.y + w2 * E.z + w3 * E.w;                 \
    _Pragma("unroll") for (int d = 0; d < 8; ++d)                          \
      dot = fmaf(q[d], bf2f((ushort)K[d]), dot);                           \
    dot += __shfl_xor(dot, 1);                                             \
    dot += __shfl_xor(dot, 2);                                             \
    dot += __shfl_xor(dot, 4);                                             \
    dot += __shfl_xor(dot, 8);                                             \
    float p = (valid) ? __expf(dot) : 0.f;                                 \
    s_acc += p;                                                            \
    _Pragma("unroll") for (int d = 0; d < 8; ++d)                          \
      av[d] = fmaf(p, bf2f((ushort)V[d]), av[d]);                          \
    ae[0] = fmaf(p, E.x, ae[0]); ae[1] = fmaf(p, E.y, ae[1]);              \
    ae[2] = fmaf(p, E.z, ae[2]); ae[3] = fmaf(p, E.w, ae[3]);              \
  }
#define ECOMP(K0, K1, V0, V1, E0, E1, base)                                \
  {                                                                        \
    ESLOT(K0, V0, E0, (base) + grp < end);                                 \
    ESLOT(K1, V1, E1, (base) + 4 + grp < end);                             \
  }

    bf16x8 kA0, kA1, vA0, vA1, kB0, kB1, vB0, vB1;
    float4 eA0, eA1, eB0, eB1;
    int i0 = wnd;
    ELOAD(kA0, kA1, vA0, vA1, eA0, eA1, i0);
    while (true) {
      int i1 = i0 + 8;
      if (i1 < wend) ELOAD(kB0, kB1, vB0, vB1, eB0, eB1, i1);
      ECOMP(kA0, kA1, vA0, vA1, eA0, eA1, i0);
      i0 = i1;
      if (i0 >= wend) break;
      int i2 = i0 + 8;
      if (i2 < wend) ELOAD(kA0, kA1, vA0, vA1, eA0, eA1, i2);
      ECOMP(kB0, kB1, vB0, vB1, eB0, eB1, i0);
      i0 = i2;
      if (i0 >= wend) break;
    }
#undef ELOAD
#undef ESLOT
#undef ECOMP
  }

  s_acc += __shfl_xor(s_acc, 16); s_acc += __shfl_xor(s_acc, 32);
  #pragma unroll
  for (int d = 0; d < 8; ++d) {
    av[d] += __shfl_xor(av[d], 16);
    av[d] += __shfl_xor(av[d], 32);
  }
  #pragma unroll
  for (int d = 0; d < 4; ++d) {
    ae[d] += __shfl_xor(ae[d], 16);
    ae[d] += __shfl_xor(ae[d], 32);
  }
  if (grp == 0) {
    if (l15 == 0) sden[n] = s_acc;
    float4 o0 = {av[0], av[1], av[2], av[3]};
    float4 o1 = {av[4], av[5], av[6], av[7]};
    float* vr = &vaccf[(size_t)n * 128 + l15 * 8];
    *(float4*)vr = o0;
    *(float4*)(vr + 4) = o1;
    ushort4 eo;
    eo.x = f2bf(ae[0]); eo.y = f2bf(ae[1]); eo.z = f2bf(ae[2]); eo.w = f2bf(ae[3]);
    *(ushort4*)&ewb[(size_t)n * DE + l15 * 4] = eo;
  }
}

// ---------- fused EWE GEMM + finalize via LDS ewout tile ----------
__global__ __launch_bounds__(256) void k_ewefin(const ushort* __restrict__ ewb,
                                                const ushort* __restrict__ Wp3,
                                                const float* __restrict__ sden,
                                                const float* __restrict__ vaccf,
                                                const ushort* __restrict__ hrb,
                                                const float* __restrict__ gamma,
                                                const float* __restrict__ beta,
                                                float* __restrict__ ynorm, int nN) {
  __shared__ float elds[16][132];
  int lane = threadIdx.x & 63, wave = threadIdx.x >> 6;
  int l15 = lane & 15, lh = lane >> 4;
  int m0 = blockIdx.x * 16;
  // ---- phase A ----
  {
    int rowa = m0 + l15; if (rowa >= nN) rowa = nN - 1;
    f32x4 acc[2] = {};
    #pragma unroll
    for (int s = 0; s < 2; ++s) {
      bf16x8 af = *(const bf16x8*)&ewb[(size_t)rowa * DE + s * 32 + lh * 8];
      #pragma unroll
      for (int tt = 0; tt < 2; ++tt) {
        int t = wave * 2 + tt;
        bf16x8 bf = *(const bf16x8*)&Wp3[((t * 2 + s) * 64 + lane) * 8];
        acc[tt] = __builtin_amdgcn_mfma_f32_16x16x32_bf16(af, bf, acc[tt], 0, 0, 0);
      }
    }
    #pragma unroll
    for (int tt = 0; tt < 2; ++tt) {
      int c = (wave * 2 + tt) * 16 + l15;
      #pragma unroll
      for (int r = 0; r < 4; ++r) elds[lh * 4 + r][c] = acc[tt][r];
    }
  }
  __syncthreads();
  // ---- phase B: 4 rows per wave ----
  int grp = lane >> 5, l5 = lane & 31;
  #pragma unroll
  for (int rr = 0; rr < 2; ++rr) {
    int rl = wave * 4 + rr * 2 + grp;
    int n = m0 + rl;
    if (n >= nN) continue;
    float s = sden[n];
    float inv = (s > 0.f) ? 1.f / s : 0.f;
    float4 v4 = *(const float4*)&vaccf[(size_t)n * 128 + l5 * 4];
    float4 w4 = *(const float4*)&elds[rl][l5 * 4];
    ushort4 hv = *(const ushort4*)&hrb[(size_t)n * 128 + l5 * 4];
    float4 o4;
    o4.x = (v4.x + w4.x) * inv + bf2f(hv.x);
    o4.y = (v4.y + w4.y) * inv + bf2f(hv.y);
    o4.z = (v4.z + w4.z) * inv + bf2f(hv.z);
    o4.w = (v4.w + w4.w) * inv + bf2f(hv.w);
    float s1 = o4.x + o4.y + o4.z + o4.w;
    float sq = o4.x*o4.x + o4.y*o4.y + o4.z*o4.z + o4.w*o4.w;
    #pragma unroll
    for (int off = 1; off < 32; off <<= 1) {
      s1 += __shfl_xor(s1, off);
      sq += __shfl_xor(sq, off);
    }
    float mu = s1 * (1.f / 128.f);
    float var = sq * (1.f / 128.f) - mu * mu;
    float rstd = rsqrtf(var + 1e-5f);
    float4 g4 = *(const float4*)&gamma[l5 * 4];
    float4 b4 = *(const float4*)&beta[l5 * 4];
    float4 y;
    y.x = fmaxf((o4.x - mu) * rstd * g4.x + b4.x, 0.f);
    y.y = fmaxf((o4.y - mu) * rstd * g4.y + b4.y, 0.f);
    y.z = fmaxf((o4.z - mu) * rstd * g4.z + b4.z, 0.f);
    y.w = fmaxf((o4.w - mu) * rstd * g4.w + b4.w, 0.f);
    *(float4*)&ynorm[(size_t)n * 128 + l5 * 4] = y;
  }
}

// ---------- segmented mean pool: one block per graph, contiguous node range ----------
__global__ __launch_bounds__(128) void k_pool(const float* __restrict__ ynorm,
                                              const int* __restrict__ gstart,
                                              float* __restrict__ out) {
  int b = blockIdx.x, t = threadIdx.x;
  int beg = gstart[b], end = gstart[b + 1];
  float a0 = 0.f, a1 = 0.f, a2 = 0.f, a3 = 0.f;
  int n = beg;
  for (; n + 4 <= end; n += 4) {
    a0 += ynorm[(size_t)(n + 0) * 128 + t];
    a1 += ynorm[(size_t)(n + 1) * 128 + t];
    a2 += ynorm[(size_t)(n + 2) * 128 + t];
    a3 += ynorm[(size_t)(n + 3) * 128 + t];
  }
  for (; n < end; ++n) a0 += ynorm[(size_t)n * 128 + t];
  float acc = (a0 + a1) + (a2 + a3);
  out[b * 128 + t] = acc / fmaxf((float)(end - beg), 1.f);
}

extern "C" void kernel_launch(void* const* d_in, const int* in_sizes, int n_in,
                              void* d_out, int out_size, void* d_ws, size_t ws_size,
                              hipStream_t stream) {
  const float* x         = (const float*)d_in[0];
  const float* edge_attr = (const float*)d_in[1];
  const int*   edge_index= (const int*)d_in[2];
  const int*   batch     = (const int*)d_in[3];
  const float* W1 = (const float*)d_in[4];
  const float* b1 = (const float*)d_in[5];
  const float* Wq = (const float*)d_in[6];  const float* bq = (const float*)d_in[7];
  const float* Wk = (const float*)d_in[8];  const float* bk = (const float*)d_in[9];
  const float* Wv = (const float*)d_in[10]; const float* bv = (const float*)d_in[11];
  const float* We = (const float*)d_in[12]; const float* be = (const float*)d_in[13];
  const float* Wr = (const float*)d_in[14]; const float* br = (const float*)d_in[15];
  const float* gamma = (const float*)d_in[16];
  const float* beta  = (const float*)d_in[17];
  float* out = (float*)d_out;

  const int nN = in_sizes[0] / DN;       // 50000
  const int nE = in_sizes[1] / DE;       // 1600000
  const int B  = out_size / DEMB;        // 64

  char* p = (char*)d_ws;
  auto alloc = [&](size_t bytes) -> void* {
    void* r = (void*)p;
    p += (bytes + 255) & ~(size_t)255;
    return r;
  };
  // ---- zeroed region ----
  int*   degi   = (int*)  alloc((size_t)nN * 4);
  int*   cursor = (int*)  alloc((size_t)nN * 4);
  size_t zero_bytes = (size_t)(p - (char*)d_ws);
  // ---- non-zeroed ----
  int*    row_ptr = (int*)   alloc((size_t)(nN + 1) * 4);
  int*    gstart  = (int*)   alloc((size_t)(B + 1) * 4);
  float*  dinv    = (float*) alloc((size_t)nN * 4);
  int2*   csr_se  = (int2*)  alloc((size_t)nE * 8);
  ushort* Wp1     = (ushort*)alloc((size_t)16 * 4 * 64 * 8 * 2);
  ushort* Wp2     = (ushort*)alloc((size_t)36 * 8 * 64 * 8 * 2);
  ushort* Wp3     = (ushort*)alloc((size_t)8 * 2 * 64 * 8 * 2);
  float*  bcat    = (float*) alloc(576 * 4);
  ushort* qwb     = (ushort*)alloc((size_t)nN * 192 * 2);
  ushort* hrb     = (ushort*)alloc((size_t)nN * 128 * 2);
  ushort* xsb     = (ushort*)alloc((size_t)nN * DN * 2);   // dead after k_gcnX
  ushort* aggxb   = (ushort*)alloc((size_t)nN * DN * 2);   // live through k_gemm12 phase A
  ushort* kvb     = (ushort*)alloc((size_t)nN * 256 * 2);  // own buffer
  float*  sden    = (float*) alloc((size_t)nN * 4);
  float*  vaccf   = (float*) alloc((size_t)nN * 128 * 4);
  ushort* ewb     = (ushort*)alloc((size_t)nN * DE * 2);
  float*  ynorm   = (float*) alloc((size_t)nN * 128 * 4);
  size_t required = (size_t)(p - (char*)d_ws);
  if (ws_size < required) return;

  hipMemsetAsync(d_ws, 0, zero_bytes, stream);

  k_prep_all<<<739, 256, 0, stream>>>(W1, Wq, Wk, Wv, Wr, We, bq, bk, bv, br, be,
                                      Wp1, Wp2, Wp3, bcat);
  k_deg<<<(nE + 255) / 256, 256, 0, stream>>>(edge_index, degi, nE);
  k_scan<<<1, 1024, 0, stream>>>(degi, row_ptr, dinv, nN);
  k_scatter<<<(nE + 255) / 256, 256, 0, stream>>>(edge_index, row_ptr, cursor,
                                                  csr_se, nE);
  k_xcast<<<(nN * 32 + 255) / 256, 256, 0, stream>>>(x, dinv, batch, gstart, xsb,
                                                     nN, B);
  k_gcnX<<<(nN + 3) / 4, 256, 0, stream>>>(xsb, csr_se, row_ptr, dinv, aggxb, nN);
  k_gemm12<<<(nN + 15) / 16, 256, 0, stream>>>(aggxb, Wp1, b1, Wp2, bcat,
                                               qwb, kvb, hrb, nN);
  k_edge<<<(nN + 3) / 4, 256, 0, stream>>>(qwb, kvb, edge_attr, csr_se, row_ptr,
                                           sden, vaccf, ewb, nN);
  k_ewefin<<<(nN + 15) / 16, 256, 0, stream>>>(ewb, Wp3, sden, vaccf, hrb,
                                               gamma, beta, ynorm, nN);
  k_pool<<<B, 128, 0, stream>>>(ynorm, gstart, out);
}

// Round 17
// 578.402 us; speedup vs baseline: 1.4299x; 1.0163x over previous
//
#include <hip/hip_runtime.h>

typedef short bf16x8 __attribute__((ext_vector_type(8)));
typedef float f32x4 __attribute__((ext_vector_type(4)));

#define DN 128
#define DE 64
#define DEMB 128
#define DHID 256
#define SCALE 0.08838834764831845f  // 1/sqrt(128)

__device__ __forceinline__ ushort f2bf(float f) {
  unsigned u = __float_as_uint(f);
  return (ushort)((u + 0x7FFFu + ((u >> 16) & 1u)) >> 16);  // RNE
}
__device__ __forceinline__ float bf2f(ushort u) {
  return __uint_as_float((unsigned)u << 16);
}

// ---------- fused weight prep + degree count ----------
// blocks [0,576): Wp2 | [576,704): Wp1 | [704,736): Wp3 | [736,739): bcat | [739,...): k_deg
__global__ void k_prep_deg(const float* __restrict__ W1, const float* __restrict__ Wq,
                           const float* __restrict__ Wk, const float* __restrict__ Wv,
                           const float* __restrict__ Wr, const float* __restrict__ We,
                           const float* __restrict__ bq, const float* __restrict__ bk,
                           const float* __restrict__ bv, const float* __restrict__ br,
                           const float* __restrict__ be,
                           ushort* __restrict__ Wp1, ushort* __restrict__ Wp2,
                           ushort* __restrict__ Wp3, float* __restrict__ bcat,
                           const int* __restrict__ ei, int* __restrict__ degi, int nE) {
  int bid = blockIdx.x;
  if (bid >= 739) {
    int e = (bid - 739) * 256 + threadIdx.x;
    if (e < nE) atomicAdd(&degi[ei[nE + e]], 1);
    return;
  }
  if (bid < 576) {
    int idx = bid * 256 + threadIdx.x;
    int j = idx & 7, lane = (idx >> 3) & 63, s = (idx >> 9) & 7, t = idx >> 12;
    int k = s * 32 + (lane >> 4) * 8 + j;
    int c = t * 16 + (lane & 15);
    float v;
    if (c < 128)       v = Wq[k * DEMB + c] * SCALE;
    else if (c < 256)  v = Wk[k * DEMB + (c - 128)];
    else if (c < 384)  v = Wv[k * DEMB + (c - 256)];
    else if (c < 512)  v = Wr[k * DEMB + (c - 384)];
    else {
      int cc = c - 512;
      float a = 0.f;
      for (int u = 0; u < DEMB; ++u) a += Wq[k * DEMB + u] * We[cc * DEMB + u];
      v = a * SCALE;
    }
    Wp2[idx] = f2bf(v);
  } else if (bid < 704) {
    int idx = (bid - 576) * 256 + threadIdx.x;
    int j = idx & 7, lane = (idx >> 3) & 63, s = (idx >> 9) & 3, t = idx >> 11;
    int k = s * 32 + (lane >> 4) * 8 + j;
    int c = t * 16 + (lane & 15);
    Wp1[idx] = f2bf(W1[k * DHID + c]);
  } else if (bid < 736) {
    int idx = (bid - 704) * 256 + threadIdx.x;
    int j = idx & 7, lane = (idx >> 3) & 63, s = (idx >> 9) & 1, t = idx >> 10;
    int k = s * 32 + (lane >> 4) * 8 + j;
    int c = t * 16 + (lane & 15);
    Wp3[idx] = f2bf(We[k * DEMB + c]);
  } else {
    int j = (bid - 736) * 256 + threadIdx.x;
    if (j >= 576) return;
    float v;
    if (j < 128)       v = bq[j] * SCALE;
    else if (j < 256)  v = bk[j - 128] + be[j - 128];
    else if (j < 384)  v = bv[j - 256] + be[j - 256];
    else if (j < 512)  v = br[j - 384];
    else {
      int cc = j - 512;
      float a = 0.f;
      for (int u = 0; u < DEMB; ++u) a += bq[u] * We[cc * DEMB + u];
      v = a * SCALE;
    }
    bcat[j] = v;
  }
}

__global__ __launch_bounds__(1024) void k_scan(const int* __restrict__ degi,
                                               int* __restrict__ row_ptr,
                                               float* __restrict__ dinv, int n) {
  __shared__ int wsum[16];
  __shared__ int carry_s;
  int lane = threadIdx.x & 63, wid = threadIdx.x >> 6;
  if (threadIdx.x == 0) carry_s = 0;
  __syncthreads();
  for (int base = 0; base < n; base += 1024) {
    int i = base + threadIdx.x;
    int v = (i < n) ? degi[i] : 0;
    if (i < n) dinv[i] = rsqrtf(1.0f + (float)v);
    int sc = v;
    #pragma unroll
    for (int off = 1; off < 64; off <<= 1) {
      int t = __shfl_up(sc, off);
      if (lane >= off) sc += t;
    }
    if (lane == 63) wsum[wid] = sc;
    int carry0 = carry_s;
    __syncthreads();
    if (wid == 0) {
      int w = (lane < 16) ? wsum[lane] : 0;
      int swc = w;
      #pragma unroll
      for (int off = 1; off < 16; off <<= 1) {
        int t = __shfl_up(swc, off);
        if (lane >= off) swc += t;
      }
      if (lane < 16) wsum[lane] = swc - w;
      if (lane == 15) carry_s = carry0 + swc;
    }
    __syncthreads();
    if (i < n) row_ptr[i] = carry0 + wsum[wid] + sc - v;
    __syncthreads();
  }
  if (threadIdx.x == 0) row_ptr[n] = carry_s;
}

// ---------- scatter + xcast + gbounds fused (all depend only on scan) ----------
// blocks [0, EB): scatter over edges | [EB, EB+XB): xcast/gbounds over nodes
__global__ __launch_bounds__(256) void k_scx(const int* __restrict__ ei,
                                             const int* __restrict__ row_ptr,
                                             int* __restrict__ cursor,
                                             int2* __restrict__ csr_se,
                                             const float* __restrict__ x,
                                             const float* __restrict__ dinv,
                                             const int* __restrict__ batch,
                                             int* __restrict__ gstart,
                                             ushort* __restrict__ xsb,
                                             int nE, int nN, int B, int EB) {
  int bid = blockIdx.x;
  if (bid < EB) {
    int e = bid * 256 + threadIdx.x;
    if (e >= nE) return;
    int dst = ei[nE + e];
    int pos = row_ptr[dst] + atomicAdd(&cursor[dst], 1);
    csr_se[pos] = make_int2(ei[e], e);
    return;
  }
  int idx = (bid - EB) * 256 + threadIdx.x;
  if (idx < nN) {
    int b = batch[idx];
    if (idx == 0) {
      for (int g = 0; g <= b; ++g) gstart[g] = 0;
    } else {
      int pb = batch[idx - 1];
      for (int g = pb + 1; g <= b; ++g) gstart[g] = idx;
    }
    if (idx == nN - 1) {
      for (int g = b + 1; g <= B; ++g) gstart[g] = nN;
    }
  }
  if (idx < nN * 32) {
    int n = idx >> 5, q = idx & 31;
    float dn = dinv[n];
    float4 v = *(const float4*)&x[(size_t)n * DN + q * 4];
    ushort4 o;
    o.x = f2bf(v.x * dn); o.y = f2bf(v.y * dn);
    o.z = f2bf(v.z * dn); o.w = f2bf(v.w * dn);
    *(ushort4*)&xsb[(size_t)n * DN + q * 4] = o;
  }
}

// ---------- GCN aggregate: bulk index preload + ping-pong; 8 nodes / 512-thr block ----------
__global__ __launch_bounds__(512) void k_gcnX(const ushort* __restrict__ xsb,
                                              const int2* __restrict__ csr_se,
                                              const int* __restrict__ row_ptr,
                                              const float* __restrict__ dinv,
                                              ushort* __restrict__ aggxb, int nN) {
  int lane = threadIdx.x & 63;
  int n = blockIdx.x * 8 + (threadIdx.x >> 6);
  if (n >= nN) return;
  int grp = lane >> 4, l15 = lane & 15;
  int beg = row_ptr[n], end = row_ptr[n + 1];
  float acc[8] = {};

  for (int w0 = beg; w0 < end; w0 += 64) {
    int wend = w0 + 64 < end ? w0 + 64 : end;
    int li = w0 + lane; if (li >= end) li = end - 1;
    int sidx = csr_se[li].x;                     // 64 src indices, coalesced

#define GLOAD(X0, X1, base)                                                \
  {                                                                        \
    int c0 = (base) + grp;     if (c0 >= wend) c0 = wend - 1;              \
    int c1 = (base) + 4 + grp; if (c1 >= wend) c1 = wend - 1;              \
    int s0 = __shfl(sidx, c0 - w0);                                        \
    int s1 = __shfl(sidx, c1 - w0);                                        \
    X0 = *(const uint4*)&xsb[(size_t)s0 * DN + l15 * 8];                   \
    X1 = *(const uint4*)&xsb[(size_t)s1 * DN + l15 * 8];                   \
  }
#define GCOMP(X0, X1, base)                                                \
  {                                                                        \
    float m0 = ((base) + grp < end) ? 1.f : 0.f;                           \
    float m1 = ((base) + 4 + grp < end) ? 1.f : 0.f;                       \
    unsigned q0[4] = {X0.x, X0.y, X0.z, X0.w};                             \
    unsigned q1[4] = {X1.x, X1.y, X1.z, X1.w};                             \
    _Pragma("unroll") for (int d = 0; d < 4; ++d) {                        \
      acc[2*d]   = fmaf(m0, __uint_as_float(q0[d] << 16), acc[2*d]);       \
      acc[2*d+1] = fmaf(m0, __uint_as_float(q0[d] & 0xFFFF0000u), acc[2*d+1]); \
      acc[2*d]   = fmaf(m1, __uint_as_float(q1[d] << 16), acc[2*d]);       \
      acc[2*d+1] = fmaf(m1, __uint_as_float(q1[d] & 0xFFFF0000u), acc[2*d+1]); \
    }                                                                      \
  }

    uint4 xA0, xA1, xB0, xB1;
    int i0 = w0;
    GLOAD(xA0, xA1, i0);
    while (true) {
      int i1 = i0 + 8;
      if (i1 < wend) GLOAD(xB0, xB1, i1);
      GCOMP(xA0, xA1, i0);
      i0 = i1;
      if (i0 >= wend) break;
      int i2 = i0 + 8;
      if (i2 < wend) GLOAD(xA0, xA1, i2);
      GCOMP(xB0, xB1, i0);
      i0 = i2;
      if (i0 >= wend) break;
    }
#undef GLOAD
#undef GCOMP
  }

  #pragma unroll
  for (int d = 0; d < 8; ++d) {
    acc[d] += __shfl_xor(acc[d], 16);
    acc[d] += __shfl_xor(acc[d], 32);
  }
  if (grp == 0) {
    uint4 sa = *(const uint4*)&xsb[(size_t)n * DN + l15 * 8];
    unsigned sq[4] = {sa.x, sa.y, sa.z, sa.w};
    float dn = dinv[n];
    ushort o[8];
    #pragma unroll
    for (int d = 0; d < 4; ++d) {
      float lo = __uint_as_float(sq[d] << 16);
      float hi = __uint_as_float(sq[d] & 0xFFFF0000u);
      o[2*d]   = f2bf(dn * (acc[2*d]   + lo));
      o[2*d+1] = f2bf(dn * (acc[2*d+1] + hi));
    }
    uint4 ov = {(unsigned)o[0] | ((unsigned)o[1] << 16),
                (unsigned)o[2] | ((unsigned)o[3] << 16),
                (unsigned)o[4] | ((unsigned)o[5] << 16),
                (unsigned)o[6] | ((unsigned)o[7] << 16)};
    *(uint4*)&aggxb[(size_t)n * DN + l15 * 8] = ov;
  }
}

// ---------- fused GEMM1b+GEMM2 via LDS hb tile ----------
__global__ __launch_bounds__(256) void k_gemm12(const ushort* __restrict__ aggxb,
                                                const ushort* __restrict__ Wp1,
                                                const float* __restrict__ b1,
                                                const ushort* __restrict__ Wp2,
                                                const float* __restrict__ bcat,
                                                ushort* __restrict__ qwb,
                                                ushort* __restrict__ kvb,
                                                ushort* __restrict__ hrb, int nN) {
  __shared__ ushort hlds[16][264];
  int lane = threadIdx.x & 63, wave = threadIdx.x >> 6;
  int l15 = lane & 15, lh = lane >> 4;
  int m0 = blockIdx.x * 16;
  int rowa = m0 + l15; if (rowa >= nN) rowa = nN - 1;
  // ---- phase A ----
  {
    f32x4 acc[4] = {};
    #pragma unroll
    for (int s = 0; s < 4; ++s) {
      bf16x8 af = *(const bf16x8*)&aggxb[(size_t)rowa * DN + s * 32 + lh * 8];
      #pragma unroll
      for (int tt = 0; tt < 4; ++tt) {
        int t = wave * 4 + tt;
        bf16x8 bf = *(const bf16x8*)&Wp1[((t * 4 + s) * 64 + lane) * 8];
        acc[tt] = __builtin_amdgcn_mfma_f32_16x16x32_bf16(af, bf, acc[tt], 0, 0, 0);
      }
    }
    #pragma unroll
    for (int tt = 0; tt < 4; ++tt) {
      int c = (wave * 4 + tt) * 16 + l15;
      float bc = b1[c];
      #pragma unroll
      for (int r = 0; r < 4; ++r)
        hlds[lh * 4 + r][c] = f2bf(fmaxf(acc[tt][r] + bc, 0.f));
    }
  }
  __syncthreads();
  // ---- phase B ----
  {
    f32x4 acc[9] = {};
    for (int s = 0; s < 8; ++s) {
      bf16x8 af = *(const bf16x8*)&hlds[l15][s * 32 + lh * 8];
      #pragma unroll
      for (int tt = 0; tt < 9; ++tt) {
        int t = wave * 9 + tt;
        bf16x8 bf = *(const bf16x8*)&Wp2[((t * 8 + s) * 64 + lane) * 8];
        acc[tt] = __builtin_amdgcn_mfma_f32_16x16x32_bf16(af, bf, acc[tt], 0, 0, 0);
      }
    }
    #pragma unroll
    for (int tt = 0; tt < 9; ++tt) {
      int c = (wave * 9 + tt) * 16 + l15;
      float bc = bcat[c];
      #pragma unroll
      for (int r = 0; r < 4; ++r) {
        int row = m0 + lh * 4 + r;
        if (row >= nN) continue;
        ushort val = f2bf(acc[tt][r] + bc);
        if (c < 128)      qwb[(size_t)row * 192 + c] = val;
        else if (c < 256) { int d = c - 128; kvb[(size_t)row * 256 + (d >> 3) * 16 + (d & 7)] = val; }
        else if (c < 384) { int d = c - 256; kvb[(size_t)row * 256 + (d >> 3) * 16 + 8 + (d & 7)] = val; }
        else if (c < 512) hrb[(size_t)row * 128 + (c - 384)] = val;
        else              qwb[(size_t)row * 192 + 128 + (c - 512)] = val;
      }
    }
  }
}

// ---------- fused attention edge pass: bulk index preload + ping-pong; 8 nodes / 512-thr ----------
__global__ __launch_bounds__(512) void k_edge(const ushort* __restrict__ qwb,
                                              const ushort* __restrict__ kvb,
                                              const float* __restrict__ ea32,
                                              const int2* __restrict__ csr_se,
                                              const int* __restrict__ row_ptr,
                                              float* __restrict__ sden,
                                              float* __restrict__ vaccf,
                                              ushort* __restrict__ ewb, int nN) {
  int lane = threadIdx.x & 63;
  int n = blockIdx.x * 8 + (threadIdx.x >> 6);
  if (n >= nN) return;
  int grp = lane >> 4, l15 = lane & 15;
  const ushort* qp = &qwb[(size_t)n * 192];
  bf16x8 qv = *(const bf16x8*)&qp[l15 * 8];
  ushort4 wv = *(const ushort4*)&qp[128 + l15 * 4];
  float q[8];
  #pragma unroll
  for (int d = 0; d < 8; ++d) q[d] = bf2f((ushort)qv[d]);
  float w0 = bf2f(wv.x), w1 = bf2f(wv.y), w2 = bf2f(wv.z), w3 = bf2f(wv.w);
  float s_acc = 0.f;
  float av[8] = {};
  float ae[4] = {};
  int beg = row_ptr[n], end = row_ptr[n + 1];

  for (int wnd = beg; wnd < end; wnd += 64) {
    int wend = wnd + 64 < end ? wnd + 64 : end;
    int li = wnd + lane; if (li >= end) li = end - 1;
    int2 sidx = csr_se[li];                      // 64 (src,eid), coalesced

#define ELOAD(K0, K1, V0, V1, E0, E1, base)                                \
  {                                                                        \
    int c0 = (base) + grp;     if (c0 >= wend) c0 = wend - 1;              \
    int c1 = (base) + 4 + grp; if (c1 >= wend) c1 = wend - 1;              \
    int sx0 = __shfl(sidx.x, c0 - wnd), sy0 = __shfl(sidx.y, c0 - wnd);    \
    int sx1 = __shfl(sidx.x, c1 - wnd), sy1 = __shfl(sidx.y, c1 - wnd);    \
    const ushort* r0 = &kvb[(size_t)sx0 * 256 + l15 * 16];                 \
    const ushort* r1 = &kvb[(size_t)sx1 * 256 + l15 * 16];                 \
    K0 = *(const bf16x8*)r0;  V0 = *(const bf16x8*)(r0 + 8);               \
    K1 = *(const bf16x8*)r1;  V1 = *(const bf16x8*)(r1 + 8);               \
    E0 = *(const float4*)&ea32[(size_t)sy0 * DE + l15 * 4];                \
    E1 = *(const float4*)&ea32[(size_t)sy1 * DE + l15 * 4];                \
  }
#define ESLOT(K, V, E, valid)                                              \
  {                                                                        \
    float dot = w0 * E.x + w1 * E.y + w2 * E.z + w3 * E.w;                 \
    _Pragma("unroll") for (int d = 0; d < 8; ++d)                          \
      dot = fmaf(q[d], bf2f((ushort)K[d]), dot);                           \
    dot += __shfl_xor(dot, 1);                                             \
    dot += __shfl_xor(dot, 2);                                             \
    dot += __shfl_xor(dot, 4);                                             \
    dot += __shfl_xor(dot, 8);                                             \
    float p = (valid) ? __expf(dot) : 0.f;                                 \
    s_acc += p;                                                            \
    _Pragma("unroll") for (int d = 0; d < 8; ++d)                          \
      av[d] = fmaf(p, bf2f((ushort)V[d]), av[d]);                          \
    ae[0] = fmaf(p, E.x, ae[0]); ae[1] = fmaf(p, E.y, ae[1]);              \
    ae[2] = fmaf(p, E.z, ae[2]); ae[3] = fmaf(p, E.w, ae[3]);              \
  }
#define ECOMP(K0, K1, V0, V1, E0, E1, base)                                \
  {                                                                        \
    ESLOT(K0, V0, E0, (base) + grp < end);                                 \
    ESLOT(K1, V1, E1, (base) + 4 + grp < end);                             \
  }

    bf16x8 kA0, kA1, vA0, vA1, kB0, kB1, vB0, vB1;
    float4 eA0, eA1, eB0, eB1;
    int i0 = wnd;
    ELOAD(kA0, kA1, vA0, vA1, eA0, eA1, i0);
    while (true) {
      int i1 = i0 + 8;
      if (i1 < wend) ELOAD(kB0, kB1, vB0, vB1, eB0, eB1, i1);
      ECOMP(kA0, kA1, vA0, vA1, eA0, eA1, i0);
      i0 = i1;
      if (i0 >= wend) break;
      int i2 = i0 + 8;
      if (i2 < wend) ELOAD(kA0, kA1, vA0, vA1, eA0, eA1, i2);
      ECOMP(kB0, kB1, vB0, vB1, eB0, eB1, i0);
      i0 = i2;
      if (i0 >= wend) break;
    }
#undef ELOAD
#undef ESLOT
#undef ECOMP
  }

  s_acc += __shfl_xor(s_acc, 16); s_acc += __shfl_xor(s_acc, 32);
  #pragma unroll
  for (int d = 0; d < 8; ++d) {
    av[d] += __shfl_xor(av[d], 16);
    av[d] += __shfl_xor(av[d], 32);
  }
  #pragma unroll
  for (int d = 0; d < 4; ++d) {
    ae[d] += __shfl_xor(ae[d], 16);
    ae[d] += __shfl_xor(ae[d], 32);
  }
  if (grp == 0) {
    if (l15 == 0) sden[n] = s_acc;
    float4 o0 = {av[0], av[1], av[2], av[3]};
    float4 o1 = {av[4], av[5], av[6], av[7]};
    float* vr = &vaccf[(size_t)n * 128 + l15 * 8];
    *(float4*)vr = o0;
    *(float4*)(vr + 4) = o1;
    ushort4 eo;
    eo.x = f2bf(ae[0]); eo.y = f2bf(ae[1]); eo.z = f2bf(ae[2]); eo.w = f2bf(ae[3]);
    *(ushort4*)&ewb[(size_t)n * DE + l15 * 4] = eo;
  }
}

// ---------- fused EWE GEMM + finalize via LDS ewout tile ----------
__global__ __launch_bounds__(256) void k_ewefin(const ushort* __restrict__ ewb,
                                                const ushort* __restrict__ Wp3,
                                                const float* __restrict__ sden,
                                                const float* __restrict__ vaccf,
                                                const ushort* __restrict__ hrb,
                                                const float* __restrict__ gamma,
                                                const float* __restrict__ beta,
                                                float* __restrict__ ynorm, int nN) {
  __shared__ float elds[16][132];
  int lane = threadIdx.x & 63, wave = threadIdx.x >> 6;
  int l15 = lane & 15, lh = lane >> 4;
  int m0 = blockIdx.x * 16;
  // ---- phase A ----
  {
    int rowa = m0 + l15; if (rowa >= nN) rowa = nN - 1;
    f32x4 acc[2] = {};
    #pragma unroll
    for (int s = 0; s < 2; ++s) {
      bf16x8 af = *(const bf16x8*)&ewb[(size_t)rowa * DE + s * 32 + lh * 8];
      #pragma unroll
      for (int tt = 0; tt < 2; ++tt) {
        int t = wave * 2 + tt;
        bf16x8 bf = *(const bf16x8*)&Wp3[((t * 2 + s) * 64 + lane) * 8];
        acc[tt] = __builtin_amdgcn_mfma_f32_16x16x32_bf16(af, bf, acc[tt], 0, 0, 0);
      }
    }
    #pragma unroll
    for (int tt = 0; tt < 2; ++tt) {
      int c = (wave * 2 + tt) * 16 + l15;
      #pragma unroll
      for (int r = 0; r < 4; ++r) elds[lh * 4 + r][c] = acc[tt][r];
    }
  }
  __syncthreads();
  // ---- phase B: 4 rows per wave ----
  int grp = lane >> 5, l5 = lane & 31;
  #pragma unroll
  for (int rr = 0; rr < 2; ++rr) {
    int rl = wave * 4 + rr * 2 + grp;
    int n = m0 + rl;
    if (n >= nN) continue;
    float s = sden[n];
    float inv = (s > 0.f) ? 1.f / s : 0.f;
    float4 v4 = *(const float4*)&vaccf[(size_t)n * 128 + l5 * 4];
    float4 w4 = *(const float4*)&elds[rl][l5 * 4];
    ushort4 hv = *(const ushort4*)&hrb[(size_t)n * 128 + l5 * 4];
    float4 o4;
    o4.x = (v4.x + w4.x) * inv + bf2f(hv.x);
    o4.y = (v4.y + w4.y) * inv + bf2f(hv.y);
    o4.z = (v4.z + w4.z) * inv + bf2f(hv.z);
    o4.w = (v4.w + w4.w) * inv + bf2f(hv.w);
    float s1 = o4.x + o4.y + o4.z + o4.w;
    float sq = o4.x*o4.x + o4.y*o4.y + o4.z*o4.z + o4.w*o4.w;
    #pragma unroll
    for (int off = 1; off < 32; off <<= 1) {
      s1 += __shfl_xor(s1, off);
      sq += __shfl_xor(sq, off);
    }
    float mu = s1 * (1.f / 128.f);
    float var = sq * (1.f / 128.f) - mu * mu;
    float rstd = rsqrtf(var + 1e-5f);
    float4 g4 = *(const float4*)&gamma[l5 * 4];
    float4 b4 = *(const float4*)&beta[l5 * 4];
    float4 y;
    y.x = fmaxf((o4.x - mu) * rstd * g4.x + b4.x, 0.f);
    y.y = fmaxf((o4.y - mu) * rstd * g4.y + b4.y, 0.f);
    y.z = fmaxf((o4.z - mu) * rstd * g4.z + b4.z, 0.f);
    y.w = fmaxf((o4.w - mu) * rstd * g4.w + b4.w, 0.f);
    *(float4*)&ynorm[(size_t)n * 128 + l5 * 4] = y;
  }
}

// ---------- segmented mean pool: one block per graph, contiguous node range ----------
__global__ __launch_bounds__(128) void k_pool(const float* __restrict__ ynorm,
                                              const int* __restrict__ gstart,
                                              float* __restrict__ out) {
  int b = blockIdx.x, t = threadIdx.x;
  int beg = gstart[b], end = gstart[b + 1];
  float a0 = 0.f, a1 = 0.f, a2 = 0.f, a3 = 0.f;
  int n = beg;
  for (; n + 4 <= end; n += 4) {
    a0 += ynorm[(size_t)(n + 0) * 128 + t];
    a1 += ynorm[(size_t)(n + 1) * 128 + t];
    a2 += ynorm[(size_t)(n + 2) * 128 + t];
    a3 += ynorm[(size_t)(n + 3) * 128 + t];
  }
  for (; n < end; ++n) a0 += ynorm[(size_t)n * 128 + t];
  float acc = (a0 + a1) + (a2 + a3);
  out[b * 128 + t] = acc / fmaxf((float)(end - beg), 1.f);
}

extern "C" void kernel_launch(void* const* d_in, const int* in_sizes, int n_in,
                              void* d_out, int out_size, void* d_ws, size_t ws_size,
                              hipStream_t stream) {
  const float* x         = (const float*)d_in[0];
  const float* edge_attr = (const float*)d_in[1];
  const int*   edge_index= (const int*)d_in[2];
  const int*   batch     = (const int*)d_in[3];
  const float* W1 = (const float*)d_in[4];
  const float* b1 = (const float*)d_in[5];
  const float* Wq = (const float*)d_in[6];  const float* bq = (const float*)d_in[7];
  const float* Wk = (const float*)d_in[8];  const float* bk = (const float*)d_in[9];
  const float* Wv = (const float*)d_in[10]; const float* bv = (const float*)d_in[11];
  const float* We = (const float*)d_in[12]; const float* be = (const float*)d_in[13];
  const float* Wr = (const float*)d_in[14]; const float* br = (const float*)d_in[15];
  const float* gamma = (const float*)d_in[16];
  const float* beta  = (const float*)d_in[17];
  float* out = (float*)d_out;

  const int nN = in_sizes[0] / DN;       // 50000
  const int nE = in_sizes[1] / DE;       // 1600000
  const int B  = out_size / DEMB;        // 64

  char* p = (char*)d_ws;
  auto alloc = [&](size_t bytes) -> void* {
    void* r = (void*)p;
    p += (bytes + 255) & ~(size_t)255;
    return r;
  };
  // ---- zeroed region ----
  int*   degi   = (int*)  alloc((size_t)nN * 4);
  int*   cursor = (int*)  alloc((size_t)nN * 4);
  size_t zero_bytes = (size_t)(p - (char*)d_ws);
  // ---- non-zeroed ----
  int*    row_ptr = (int*)   alloc((size_t)(nN + 1) * 4);
  int*    gstart  = (int*)   alloc((size_t)(B + 1) * 4);
  float*  dinv    = (float*) alloc((size_t)nN * 4);
  int2*   csr_se  = (int2*)  alloc((size_t)nE * 8);
  ushort* Wp1     = (ushort*)alloc((size_t)16 * 4 * 64 * 8 * 2);
  ushort* Wp2     = (ushort*)alloc((size_t)36 * 8 * 64 * 8 * 2);
  ushort* Wp3     = (ushort*)alloc((size_t)8 * 2 * 64 * 8 * 2);
  float*  bcat    = (float*) alloc(576 * 4);
  ushort* qwb     = (ushort*)alloc((size_t)nN * 192 * 2);
  ushort* hrb     = (ushort*)alloc((size_t)nN * 128 * 2);
  ushort* xsb     = (ushort*)alloc((size_t)nN * DN * 2);   // dead after k_gcnX
  ushort* aggxb   = (ushort*)alloc((size_t)nN * DN * 2);   // live through k_gemm12 phase A
  ushort* kvb     = (ushort*)alloc((size_t)nN * 256 * 2);  // own buffer
  float*  sden    = (float*) alloc((size_t)nN * 4);
  float*  vaccf   = (float*) alloc((size_t)nN * 128 * 4);
  ushort* ewb     = (ushort*)alloc((size_t)nN * DE * 2);
  float*  ynorm   = (float*) alloc((size_t)nN * 128 * 4);
  size_t required = (size_t)(p - (char*)d_ws);
  if (ws_size < required) return;

  hipMemsetAsync(d_ws, 0, zero_bytes, stream);

  {
    int degB = (nE + 255) / 256;
    k_prep_deg<<<739 + degB, 256, 0, stream>>>(W1, Wq, Wk, Wv, Wr, We,
                                               bq, bk, bv, br, be,
                                               Wp1, Wp2, Wp3, bcat,
                                               edge_index, degi, nE);
  }
  k_scan<<<1, 1024, 0, stream>>>(degi, row_ptr, dinv, nN);
  {
    int EB = (nE + 255) / 256;
    int XB = (nN * 32 + 255) / 256;
    k_scx<<<EB + XB, 256, 0, stream>>>(edge_index, row_ptr, cursor, csr_se,
                                       x, dinv, batch, gstart, xsb, nE, nN, B, EB);
  }
  k_gcnX<<<(nN + 7) / 8, 512, 0, stream>>>(xsb, csr_se, row_ptr, dinv, aggxb, nN);
  k_gemm12<<<(nN + 15) / 16, 256, 0, stream>>>(aggxb, Wp1, b1, Wp2, bcat,
                                               qwb, kvb, hrb, nN);
  k_edge<<<(nN + 7) / 8, 512, 0, stream>>>(qwb, kvb, edge_attr, csr_se, row_ptr,
                                           sden, vaccf, ewb, nN);
  k_ewefin<<<(nN + 15) / 16, 256, 0, stream>>>(ewb, Wp3, sden, vaccf, hrb,
                                               gamma, beta, ynorm, nN);
  k_pool<<<B, 128, 0, stream>>>(ynorm, gstart, out);
}